// Round 2
// baseline (597.859 us; speedup 1.0000x reference)
//
#include <hip/hip_runtime.h>
#include <hip/hip_bf16.h>

// ---------------------------------------------------------------------------
// PagedHSTUInferLayer on MI355X (gfx950)
// LN -> GEMM1(bf16 MFMA, silu+bias, alpha folded into q cols) ->
// HSTU attention (4-way t-split partial sums, 2 blocks/CU, cvt_pk staging) ->
// gated LN (sums four t-partials) -> GEMM2(+residual, fp32 out)
// ---------------------------------------------------------------------------

typedef __attribute__((ext_vector_type(8))) short v8s;   // 8 x bf16 (4 VGPR)
typedef __attribute__((ext_vector_type(4))) float v4f;   // MFMA accumulator
typedef __attribute__((ext_vector_type(4))) unsigned short v4us;
typedef __attribute__((ext_vector_type(4))) unsigned int v4u;

#define D_HID 512
#define U_DIM 2048
#define NHEAD 4
#define DHEAD 128
#define BATCH 32
#define SEQ   256
#define HIST  2048
#define NTOK  8192
#define ALPHA_ 0.08838834764831845f   // 1/sqrt(128)
#define EPS_   1e-5f

__device__ __forceinline__ unsigned short f2bf(float f) {
  unsigned int u = __float_as_uint(f);
  u += 0x7FFFu + ((u >> 16) & 1u);            // round-to-nearest-even
  return (unsigned short)(u >> 16);
}
__device__ __forceinline__ float bf2f(unsigned short s) {
  return __uint_as_float(((unsigned int)s) << 16);
}
__device__ __forceinline__ float siluf(float x) {
  return x / (1.0f + __expf(-x));
}
// packed 2xf32 -> 2xbf16 (v_cvt_pk_bf16_f32), lo in bits 0-15
__device__ __forceinline__ unsigned int cvtpk(float lo, float hi) {
  __hip_bfloat162 h = __float22bfloat162_rn(make_float2(lo, hi));
  union { __hip_bfloat162 h; unsigned int u; } cv; cv.h = h;
  return cv.u;
}

// ---------------------------------------------------------------------------
// LN over D=512 per row -> bf16. 4 waves/block, one row per wave.
// ---------------------------------------------------------------------------
__global__ __launch_bounds__(256) void ln_in_kernel(
    const float* __restrict__ x, const float* __restrict__ w,
    const float* __restrict__ b, unsigned short* __restrict__ out)
{
  int wid = threadIdx.x >> 6, lane = threadIdx.x & 63;
  int row = blockIdx.x * 4 + wid;
  const float* xr = x + (size_t)row * D_HID + lane * 8;
  float4 a0 = *(const float4*)xr;
  float4 a1 = *(const float4*)(xr + 4);
  float v[8] = {a0.x, a0.y, a0.z, a0.w, a1.x, a1.y, a1.z, a1.w};
  float s = 0.f, s2 = 0.f;
#pragma unroll
  for (int j = 0; j < 8; ++j) { s += v[j]; s2 += v[j] * v[j]; }
#pragma unroll
  for (int m = 1; m < 64; m <<= 1) { s += __shfl_xor(s, m, 64); s2 += __shfl_xor(s2, m, 64); }
  float mean = s * (1.f / D_HID);
  float var  = s2 * (1.f / D_HID) - mean * mean;
  float rstd = rsqrtf(var + EPS_);
  const float* wp = w + lane * 8; const float* bp = b + lane * 8;
  float4 w0 = *(const float4*)wp, w1 = *(const float4*)(wp + 4);
  float4 b0 = *(const float4*)bp, b1 = *(const float4*)(bp + 4);
  float wv[8] = {w0.x, w0.y, w0.z, w0.w, w1.x, w1.y, w1.z, w1.w};
  float bv[8] = {b0.x, b0.y, b0.z, b0.w, b1.x, b1.y, b1.z, b1.w};
  v8s o;
#pragma unroll
  for (int j = 0; j < 8; ++j) o[j] = (short)f2bf((v[j] - mean) * rstd * wv[j] + bv[j]);
  *(v8s*)(out + (size_t)row * D_HID + lane * 8) = o;
}

// ---------------------------------------------------------------------------
// gated LN: parallel = u * LN(attn0+attn1+attn2+attn3)
// ---------------------------------------------------------------------------
__global__ __launch_bounds__(256) void gated_ln_kernel(
    const float* __restrict__ attn0, const float* __restrict__ attn1,
    const float* __restrict__ attn2, const float* __restrict__ attn3,
    const unsigned short* __restrict__ uvqk,
    const float* __restrict__ w, const float* __restrict__ b,
    unsigned short* __restrict__ par)
{
  int wid = threadIdx.x >> 6, lane = threadIdx.x & 63;
  int row = blockIdx.x * 4 + wid;
  size_t off = (size_t)row * D_HID + lane * 8;
  float4 x0 = *(const float4*)(attn0 + off), x1 = *(const float4*)(attn0 + off + 4);
  float4 y0 = *(const float4*)(attn1 + off), y1 = *(const float4*)(attn1 + off + 4);
  float4 z0 = *(const float4*)(attn2 + off), z1 = *(const float4*)(attn2 + off + 4);
  float4 u0 = *(const float4*)(attn3 + off), u1 = *(const float4*)(attn3 + off + 4);
  float v[8] = {x0.x + y0.x + z0.x + u0.x, x0.y + y0.y + z0.y + u0.y,
                x0.z + y0.z + z0.z + u0.z, x0.w + y0.w + z0.w + u0.w,
                x1.x + y1.x + z1.x + u1.x, x1.y + y1.y + z1.y + u1.y,
                x1.z + y1.z + z1.z + u1.z, x1.w + y1.w + z1.w + u1.w};
  float s = 0.f, s2 = 0.f;
#pragma unroll
  for (int j = 0; j < 8; ++j) { s += v[j]; s2 += v[j] * v[j]; }
#pragma unroll
  for (int m = 1; m < 64; m <<= 1) { s += __shfl_xor(s, m, 64); s2 += __shfl_xor(s2, m, 64); }
  float mean = s * (1.f / D_HID);
  float var  = s2 * (1.f / D_HID) - mean * mean;
  float rstd = rsqrtf(var + EPS_);
  const float* wp = w + lane * 8; const float* bp = b + lane * 8;
  float4 w0 = *(const float4*)wp, w1 = *(const float4*)(wp + 4);
  float4 b0 = *(const float4*)bp, b1 = *(const float4*)(bp + 4);
  float wv[8] = {w0.x, w0.y, w0.z, w0.w, w1.x, w1.y, w1.z, w1.w};
  float bv[8] = {b0.x, b0.y, b0.z, b0.w, b1.x, b1.y, b1.z, b1.w};
  v8s uv = *(const v8s*)(uvqk + (size_t)row * U_DIM + lane * 8);
  v8s o;
#pragma unroll
  for (int j = 0; j < 8; ++j) {
    float u = bf2f((unsigned short)uv[j]);
    o[j] = (short)f2bf(u * ((v[j] - mean) * rstd * wv[j] + bv[j]));
  }
  *(v8s*)(par + (size_t)row * D_HID + lane * 8) = o;
}

// ---------------------------------------------------------------------------
// Transpose fp32 (R x C) -> bf16 (C x R).  32x32 LDS tiles.
// ---------------------------------------------------------------------------
__global__ __launch_bounds__(256) void transpose_w_kernel(
    const float* __restrict__ in, unsigned short* __restrict__ out, int R, int C)
{
  __shared__ float tile[32][33];
  int c0 = blockIdx.x * 32, r0 = blockIdx.y * 32;
  int tr = threadIdx.x >> 3;
  int tc = (threadIdx.x & 7) * 4;
  float4 vv = *(const float4*)(in + (size_t)(r0 + tr) * C + c0 + tc);
  tile[tr][tc + 0] = vv.x; tile[tr][tc + 1] = vv.y;
  tile[tr][tc + 2] = vv.z; tile[tr][tc + 3] = vv.w;
  __syncthreads();
  v4us o;
#pragma unroll
  for (int j = 0; j < 4; ++j) o[j] = f2bf(tile[tc + j][tr]);
  *(v4us*)(out + (size_t)(c0 + tr) * R + r0 + tc) = o;
}

// ---------------------------------------------------------------------------
// bf16 GEMM, 128x128 tile, BK=32, 4 waves (2x2 of 64x64), 16x16x32 MFMA.
// EPI 0: out_bf16 = silu(acc + bias[n])   (q columns additionally * ALPHA)
// EPI 1: out_f32 = acc + resid[m][n].
// ---------------------------------------------------------------------------
template <int EPI>
__global__ __launch_bounds__(256) void gemm_kernel(
    const unsigned short* __restrict__ A, const unsigned short* __restrict__ Bt,
    int K, int N,
    const float* __restrict__ bias, const float* __restrict__ resid,
    unsigned short* __restrict__ outb, float* __restrict__ outf)
{
  __shared__ unsigned short Al[128 * 40];
  __shared__ unsigned short Bl[128 * 40];
  int m0 = blockIdx.x * 128, n0 = blockIdx.y * 128;
  int tid = threadIdx.x, lane = tid & 63, wid = tid >> 6;
  int wr = wid >> 1, wc = wid & 1;
  int lr = lane & 15, lg = lane >> 4;

  v4f acc[4][4];
#pragma unroll
  for (int i = 0; i < 4; ++i)
#pragma unroll
    for (int j = 0; j < 4; ++j) acc[i][j] = (v4f){0.f, 0.f, 0.f, 0.f};

  int srow = tid >> 1;
  int sc   = (tid & 1) * 16;
  const unsigned short* ga = A  + (size_t)(m0 + srow) * K + sc;
  const unsigned short* gb = Bt + (size_t)(n0 + srow) * K + sc;

  for (int k0 = 0; k0 < K; k0 += 32) {
    v8s a0 = *(const v8s*)(ga + k0);
    v8s a1 = *(const v8s*)(ga + k0 + 8);
    v8s b0 = *(const v8s*)(gb + k0);
    v8s b1 = *(const v8s*)(gb + k0 + 8);
    *(v8s*)&Al[srow * 40 + sc]     = a0;
    *(v8s*)&Al[srow * 40 + sc + 8] = a1;
    *(v8s*)&Bl[srow * 40 + sc]     = b0;
    *(v8s*)&Bl[srow * 40 + sc + 8] = b1;
    __syncthreads();
    v8s af[4], bf[4];
#pragma unroll
    for (int mt = 0; mt < 4; ++mt) af[mt] = *(const v8s*)&Al[(wr * 64 + mt * 16 + lr) * 40 + lg * 8];
#pragma unroll
    for (int nt = 0; nt < 4; ++nt) bf[nt] = *(const v8s*)&Bl[(wc * 64 + nt * 16 + lr) * 40 + lg * 8];
#pragma unroll
    for (int mt = 0; mt < 4; ++mt)
#pragma unroll
      for (int nt = 0; nt < 4; ++nt)
        acc[mt][nt] = __builtin_amdgcn_mfma_f32_16x16x32_bf16(af[mt], bf[nt], acc[mt][nt], 0, 0, 0);
    __syncthreads();
  }

#pragma unroll
  for (int nt = 0; nt < 4; ++nt) {
    int col = n0 + wc * 64 + nt * 16 + lr;
    float bi = 0.f;
    if constexpr (EPI == 0) bi = bias[col];
#pragma unroll
    for (int mt = 0; mt < 4; ++mt) {
      int row0 = m0 + wr * 64 + mt * 16 + lg * 4;
#pragma unroll
      for (int r = 0; r < 4; ++r) {
        float xv = acc[mt][nt][r];
        if constexpr (EPI == 0) {
          float rv = siluf(xv + bi);
          if ((unsigned)(col - 2 * D_HID) < (unsigned)D_HID) rv *= ALPHA_;  // q cols
          outb[(size_t)(row0 + r) * N + col] = f2bf(rv);
        } else {
          outf[(size_t)(row0 + r) * N + col] = xv + resid[(size_t)(row0 + r) * N + col];
        }
      }
    }
  }
}

// ---------------------------------------------------------------------------
// HSTU attention, 4-way t-split.  grid = (q 4)<<7 | (b 32)<<2 | (n 4) = 512
// blocks of 512 threads (8 waves) -> 2 blocks/CU.  Each block: all 256 q rows
// of one (b,n) over 9 kv tiles of 64 (t in [q*576, q*576+576)); writes one of
// four partial-sum buffers (silu attention has no normalization).
//   Staging: thread (m = tid&15, strow = tid>>4) loads two ADJACENT t rows
//   (2*strow, 2*strow+1) x 8 d; K stored row-major via cvt_pk b128 writes;
//   V stored [d][t] with t-pair u32 writes (one cvt_pk each), XOR key
//   8*(m&7) on the t index keeping write and b128 read ~2-way free.
//   QK^T swapped (mfma(K,Q) -> S^T): P written as packed cvt_pk u32 pairs.
// ---------------------------------------------------------------------------
__global__ __launch_bounds__(512, 4) void attn_kernel(
    const float* __restrict__ histK, const float* __restrict__ histV,
    const unsigned short* __restrict__ uvqk, float* __restrict__ attn_out)
{
  __shared__ __align__(16) unsigned short Kl[64 * 136];     // [t][d], pad 8
  __shared__ __align__(16) unsigned short Vt[128 * 72];     // [d][t^key], pad 8
  __shared__ __align__(16) unsigned short Pl[8 * 32 * 72];  // per-wave [s][t]

  int bid = blockIdx.x;
  int q   = bid >> 7;
  int b   = (bid >> 2) & 31;
  int n   = bid & 3;
  int tbase0 = q * 576;

  int tid = threadIdx.x, lane = tid & 63, w = tid >> 6;
  int lr = lane & 15, lg = lane >> 4;

  // Q fragments: qf[sb][c], rows s = w*32 + sb*16 + lr
  v8s qf[2][4];
#pragma unroll
  for (int sb = 0; sb < 2; ++sb) {
    const unsigned short* qp = uvqk + (size_t)(b * SEQ + w * 32 + sb * 16 + lr) * U_DIM
                               + 2 * D_HID + n * DHEAD + lg * 8;
#pragma unroll
    for (int c = 0; c < 4; ++c) qf[sb][c] = *(const v8s*)(qp + c * 32);
  }

  v4f oacc[2][8];
#pragma unroll
  for (int sb = 0; sb < 2; ++sb)
#pragma unroll
    for (int dt = 0; dt < 8; ++dt) oacc[sb][dt] = (v4f){0.f, 0.f, 0.f, 0.f};

  int m     = tid & 15;
  int std0  = m * 8;            // staging d offset (8 contiguous)
  int strow = tid >> 4;         // staging t-pair index (0..31)
  int vkey  = 8 * (m & 7);      // Vt t-index XOR key (shorts)

  const float* kbase = histK + (((size_t)b * HIST) * NHEAD + n) * DHEAD + std0;
  const float* vbase = histV + (((size_t)b * HIST) * NHEAD + n) * DHEAD + std0;

  // staging registers (next tile in flight)
  float4 hx[2][4];              // hist: [p][k0,k1,v0,v1]
  v8s    nx[2][2];              // new-kv: [p][k,v]
  int isnew_r = 0;

  auto stage_load = [&](int kt) {
    int tb = tbase0 + kt * 64;
    if (tb < HIST) {
      isnew_r = 0;
#pragma unroll
      for (int p = 0; p < 2; ++p) {
        size_t tg = (size_t)(tb + 2 * strow + p) * (NHEAD * DHEAD);
        hx[p][0] = *(const float4*)(kbase + tg);
        hx[p][1] = *(const float4*)(kbase + tg + 4);
        hx[p][2] = *(const float4*)(vbase + tg);
        hx[p][3] = *(const float4*)(vbase + tg + 4);
      }
    } else {
      isnew_r = 1;
#pragma unroll
      for (int p = 0; p < 2; ++p) {
        int srw = b * SEQ + (tb - HIST) + 2 * strow + p;
        nx[p][0] = *(const v8s*)(uvqk + (size_t)srw * U_DIM + 3 * D_HID + n * DHEAD + std0);
        nx[p][1] = *(const v8s*)(uvqk + (size_t)srw * U_DIM + 1 * D_HID + n * DHEAD + std0);
      }
    }
  };

  auto stage_store = [&]() {
    int t0 = 2 * strow;
    if (!isnew_r) {
#pragma unroll
      for (int p = 0; p < 2; ++p) {
        v4u kp;
        kp[0] = cvtpk(hx[p][0].x, hx[p][0].y);
        kp[1] = cvtpk(hx[p][0].z, hx[p][0].w);
        kp[2] = cvtpk(hx[p][1].x, hx[p][1].y);
        kp[3] = cvtpk(hx[p][1].z, hx[p][1].w);
        *(v4u*)&Kl[(t0 + p) * 136 + std0] = kp;
      }
      float v0[8] = {hx[0][2].x, hx[0][2].y, hx[0][2].z, hx[0][2].w,
                     hx[0][3].x, hx[0][3].y, hx[0][3].z, hx[0][3].w};
      float v1[8] = {hx[1][2].x, hx[1][2].y, hx[1][2].z, hx[1][2].w,
                     hx[1][3].x, hx[1][3].y, hx[1][3].z, hx[1][3].w};
#pragma unroll
      for (int j = 0; j < 8; ++j) {
        int d = std0 + j;
        *(unsigned int*)&Vt[d * 72 + (t0 ^ vkey)] = cvtpk(v0[j], v1[j]);
      }
    } else {
#pragma unroll
      for (int p = 0; p < 2; ++p) *(v8s*)&Kl[(t0 + p) * 136 + std0] = nx[p][0];
#pragma unroll
      for (int j = 0; j < 8; ++j) {
        int d = std0 + j;
        unsigned int pk = (unsigned int)(unsigned short)nx[0][1][j]
                        | ((unsigned int)(unsigned short)nx[1][1][j] << 16);
        *(unsigned int*)&Vt[d * 72 + (t0 ^ vkey)] = pk;
      }
    }
  };

  stage_load(0);
  stage_store();
  __syncthreads();

  unsigned short* Plw = &Pl[w * 32 * 72];

  for (int kt = 0; kt < 9; ++kt) {
    if (kt + 1 < 9) stage_load(kt + 1);    // issue next-tile loads

    int tb = tbase0 + kt * 64;
    bool masked = (tb >= HIST);            // tile entirely in new-token range

    // ---- QK^T swapped: D[t][s] = K . Q^T (alpha pre-folded into q) ----
#pragma unroll
    for (int tt = 0; tt < 4; ++tt) {
      v8s kf[4];
#pragma unroll
      for (int c = 0; c < 4; ++c)
        kf[c] = *(const v8s*)&Kl[(tt * 16 + lr) * 136 + c * 32 + lg * 8];
#pragma unroll
      for (int sb = 0; sb < 2; ++sb) {
        v4f sa = (v4f){0.f, 0.f, 0.f, 0.f};
#pragma unroll
        for (int c = 0; c < 4; ++c)
          sa = __builtin_amdgcn_mfma_f32_16x16x32_bf16(kf[c], qf[sb][c], sa, 0, 0, 0);
        int s  = w * 32 + sb * 16 + lr;     // query index within SEQ
        int t0 = tb + tt * 16 + lg * 4;     // global kv position of r=0
#pragma unroll
        for (int rp = 0; rp < 2; ++rp) {
          float p0 = siluf(sa[rp * 2]);
          float p1 = siluf(sa[rp * 2 + 1]);
          if (masked) {
            if (t0 + rp * 2     - HIST > s) p0 = 0.f;   // causal: t <= H + s
            if (t0 + rp * 2 + 1 - HIST > s) p1 = 0.f;
          }
          *(unsigned int*)&Plw[(sb * 16 + lr) * 72 + tt * 16 + lg * 4 + rp * 2] =
              cvtpk(p0, p1);
        }
      }
    }

    // ---- PV: oacc += P . V  (Pl per-wave: no barrier needed between) ----
#pragma unroll
    for (int c = 0; c < 2; ++c) {
      v8s pa[2];
#pragma unroll
      for (int sb = 0; sb < 2; ++sb)
        pa[sb] = *(const v8s*)&Plw[(sb * 16 + lr) * 72 + c * 32 + lg * 8];
#pragma unroll
      for (int dt = 0; dt < 8; ++dt) {
        int d = dt * 16 + lr;
        int rkey = 8 * ((2 * dt + (lr >> 3)) & 7);     // = 8*((d>>3)&7)
        v8s vf = *(const v8s*)&Vt[d * 72 + ((c * 32 + lg * 8) ^ rkey)];
#pragma unroll
        for (int sb = 0; sb < 2; ++sb)
          oacc[sb][dt] = __builtin_amdgcn_mfma_f32_16x16x32_bf16(pa[sb], vf, oacc[sb][dt], 0, 0, 0);
      }
    }
    __syncthreads();                        // all waves done with Kl/Vt
    if (kt + 1 < 9) {
      stage_store();                        // cvt + LDS write of next tile
      __syncthreads();
    }
  }

  // ---- epilogue: write fp32 partial rows for this t-quarter ----
#pragma unroll
  for (int sb = 0; sb < 2; ++sb) {
    int srow = b * SEQ + w * 32 + sb * 16 + lg * 4;
    float* op = attn_out + (size_t)q * ((size_t)NTOK * D_HID)
              + (size_t)srow * D_HID + n * DHEAD + lr;
#pragma unroll
    for (int dt = 0; dt < 8; ++dt)
#pragma unroll
      for (int r = 0; r < 4; ++r)
        op[(size_t)r * D_HID + dt * 16] = oacc[sb][dt][r];
  }
}

// ---------------------------------------------------------------------------
extern "C" void kernel_launch(void* const* d_in, const int* in_sizes, int n_in,
                              void* d_out, int out_size, void* d_ws, size_t ws_size,
                              hipStream_t stream)
{
  (void)in_sizes; (void)n_in; (void)out_size; (void)ws_size;

  const float* layer_input = (const float*)d_in[0];
  const float* hist_k   = (const float*)d_in[1];
  const float* hist_v   = (const float*)d_in[2];
  const float* ln_in_w  = (const float*)d_in[3];
  const float* ln_in_b  = (const float*)d_in[4];
  const float* W_uvqk   = (const float*)d_in[5];
  const float* b_uvqk   = (const float*)d_in[6];
  const float* ln_out_w = (const float*)d_in[7];
  const float* ln_out_b = (const float*)d_in[8];
  const float* W_proj   = (const float*)d_in[9];
  float* out = (float*)d_out;

  // workspace layout (x_bf dead before par is written -> share [96,104)):
  char* ws = (char*)d_ws;
  unsigned short* uvqk    = (unsigned short*)(ws);                  // [  0, 32) MiB
  float*          attn0   = (float*)         (ws + (32u  << 20));   // [ 32, 48)
  float*          attn1   = (float*)         (ws + (48u  << 20));   // [ 48, 64)
  float*          attn2   = (float*)         (ws + (64u  << 20));   // [ 64, 80)
  float*          attn3   = (float*)         (ws + (80u  << 20));   // [ 80, 96)
  unsigned short* x_bf    = (unsigned short*)(ws + (96u  << 20));   // [ 96,104)
  unsigned short* par     = (unsigned short*)(ws + (96u  << 20));   // [ 96,104)
  unsigned short* wt_uvqk = (unsigned short*)(ws + (104u << 20));   // [104,106)
  unsigned short* wt_proj = (unsigned short*)(ws + (106u << 20));   // [106,106.5)

  ln_in_kernel<<<dim3(2048), dim3(256), 0, stream>>>(layer_input, ln_in_w, ln_in_b, x_bf);
  transpose_w_kernel<<<dim3(64, 16), dim3(256), 0, stream>>>(W_uvqk, wt_uvqk, 512, 2048);
  transpose_w_kernel<<<dim3(16, 16), dim3(256), 0, stream>>>(W_proj, wt_proj, 512, 512);
  gemm_kernel<0><<<dim3(64, 16), dim3(256), 0, stream>>>(x_bf, wt_uvqk, 512, 2048,
                                                         b_uvqk, nullptr, uvqk, nullptr);
  attn_kernel<<<dim3(512), dim3(512), 0, stream>>>(hist_k, hist_v, uvqk, attn0);
  gated_ln_kernel<<<dim3(2048), dim3(256), 0, stream>>>(attn0, attn1, attn2, attn3,
                                                        uvqk, ln_out_w, ln_out_b, par);
  gemm_kernel<1><<<dim3(64, 4), dim3(256), 0, stream>>>(par, wt_proj, 512, 512,
                                                        nullptr, layer_input, nullptr, out);
}

// Round 3
// 200.625 us; speedup vs baseline: 2.9800x; 2.9800x over previous
//
#include <hip/hip_runtime.h>
#include <hip/hip_bf16.h>

// ---------------------------------------------------------------------------
// PagedHSTUInferLayer on MI355X (gfx950)
// LN -> GEMM1(bf16 MFMA, silu+bias, alpha folded into q cols) ->
// HSTU attention (4-way t-split partial sums, 2 blocks/CU, cvt_pk staging) ->
// gated LN (sums four t-partials) -> GEMM2(+residual, fp32 out)
//
// NOTE: attn_kernel must NOT carry a min-waves launch_bounds hint: the kernel
// needs ~124 VGPR (acc 64 + q 32 + staging 32); forcing 4 waves/EU made the
// compiler allocate 64 VGPR and spill accumulators to scratch (WRITE_SIZE
// 33 MB -> 1.23 GB, dur 136 -> 520 us in R2). At 124 VGPR the HW already
// fits 4 waves/SIMD = 2 blocks/CU.
// ---------------------------------------------------------------------------

typedef __attribute__((ext_vector_type(8))) short v8s;   // 8 x bf16 (4 VGPR)
typedef __attribute__((ext_vector_type(4))) float v4f;   // MFMA accumulator
typedef __attribute__((ext_vector_type(4))) unsigned short v4us;
typedef __attribute__((ext_vector_type(4))) unsigned int v4u;

#define D_HID 512
#define U_DIM 2048
#define NHEAD 4
#define DHEAD 128
#define BATCH 32
#define SEQ   256
#define HIST  2048
#define NTOK  8192
#define ALPHA_ 0.08838834764831845f   // 1/sqrt(128)
#define EPS_   1e-5f

__device__ __forceinline__ unsigned short f2bf(float f) {
  unsigned int u = __float_as_uint(f);
  u += 0x7FFFu + ((u >> 16) & 1u);            // round-to-nearest-even
  return (unsigned short)(u >> 16);
}
__device__ __forceinline__ float bf2f(unsigned short s) {
  return __uint_as_float(((unsigned int)s) << 16);
}
__device__ __forceinline__ float siluf(float x) {
  return x / (1.0f + __expf(-x));
}
// packed 2xf32 -> 2xbf16 (v_cvt_pk_bf16_f32), lo in bits 0-15
__device__ __forceinline__ unsigned int cvtpk(float lo, float hi) {
  __hip_bfloat162 h = __float22bfloat162_rn(make_float2(lo, hi));
  union { __hip_bfloat162 h; unsigned int u; } cv; cv.h = h;
  return cv.u;
}

// ---------------------------------------------------------------------------
// LN over D=512 per row -> bf16. 4 waves/block, one row per wave.
// ---------------------------------------------------------------------------
__global__ __launch_bounds__(256) void ln_in_kernel(
    const float* __restrict__ x, const float* __restrict__ w,
    const float* __restrict__ b, unsigned short* __restrict__ out)
{
  int wid = threadIdx.x >> 6, lane = threadIdx.x & 63;
  int row = blockIdx.x * 4 + wid;
  const float* xr = x + (size_t)row * D_HID + lane * 8;
  float4 a0 = *(const float4*)xr;
  float4 a1 = *(const float4*)(xr + 4);
  float v[8] = {a0.x, a0.y, a0.z, a0.w, a1.x, a1.y, a1.z, a1.w};
  float s = 0.f, s2 = 0.f;
#pragma unroll
  for (int j = 0; j < 8; ++j) { s += v[j]; s2 += v[j] * v[j]; }
#pragma unroll
  for (int m = 1; m < 64; m <<= 1) { s += __shfl_xor(s, m, 64); s2 += __shfl_xor(s2, m, 64); }
  float mean = s * (1.f / D_HID);
  float var  = s2 * (1.f / D_HID) - mean * mean;
  float rstd = rsqrtf(var + EPS_);
  const float* wp = w + lane * 8; const float* bp = b + lane * 8;
  float4 w0 = *(const float4*)wp, w1 = *(const float4*)(wp + 4);
  float4 b0 = *(const float4*)bp, b1 = *(const float4*)(bp + 4);
  float wv[8] = {w0.x, w0.y, w0.z, w0.w, w1.x, w1.y, w1.z, w1.w};
  float bv[8] = {b0.x, b0.y, b0.z, b0.w, b1.x, b1.y, b1.z, b1.w};
  v8s o;
#pragma unroll
  for (int j = 0; j < 8; ++j) o[j] = (short)f2bf((v[j] - mean) * rstd * wv[j] + bv[j]);
  *(v8s*)(out + (size_t)row * D_HID + lane * 8) = o;
}

// ---------------------------------------------------------------------------
// gated LN: parallel = u * LN(attn0+attn1+attn2+attn3)
// ---------------------------------------------------------------------------
__global__ __launch_bounds__(256) void gated_ln_kernel(
    const float* __restrict__ attn0, const float* __restrict__ attn1,
    const float* __restrict__ attn2, const float* __restrict__ attn3,
    const unsigned short* __restrict__ uvqk,
    const float* __restrict__ w, const float* __restrict__ b,
    unsigned short* __restrict__ par)
{
  int wid = threadIdx.x >> 6, lane = threadIdx.x & 63;
  int row = blockIdx.x * 4 + wid;
  size_t off = (size_t)row * D_HID + lane * 8;
  float4 x0 = *(const float4*)(attn0 + off), x1 = *(const float4*)(attn0 + off + 4);
  float4 y0 = *(const float4*)(attn1 + off), y1 = *(const float4*)(attn1 + off + 4);
  float4 z0 = *(const float4*)(attn2 + off), z1 = *(const float4*)(attn2 + off + 4);
  float4 u0 = *(const float4*)(attn3 + off), u1 = *(const float4*)(attn3 + off + 4);
  float v[8] = {x0.x + y0.x + z0.x + u0.x, x0.y + y0.y + z0.y + u0.y,
                x0.z + y0.z + z0.z + u0.z, x0.w + y0.w + z0.w + u0.w,
                x1.x + y1.x + z1.x + u1.x, x1.y + y1.y + z1.y + u1.y,
                x1.z + y1.z + z1.z + u1.z, x1.w + y1.w + z1.w + u1.w};
  float s = 0.f, s2 = 0.f;
#pragma unroll
  for (int j = 0; j < 8; ++j) { s += v[j]; s2 += v[j] * v[j]; }
#pragma unroll
  for (int m = 1; m < 64; m <<= 1) { s += __shfl_xor(s, m, 64); s2 += __shfl_xor(s2, m, 64); }
  float mean = s * (1.f / D_HID);
  float var  = s2 * (1.f / D_HID) - mean * mean;
  float rstd = rsqrtf(var + EPS_);
  const float* wp = w + lane * 8; const float* bp = b + lane * 8;
  float4 w0 = *(const float4*)wp, w1 = *(const float4*)(wp + 4);
  float4 b0 = *(const float4*)bp, b1 = *(const float4*)(bp + 4);
  float wv[8] = {w0.x, w0.y, w0.z, w0.w, w1.x, w1.y, w1.z, w1.w};
  float bv[8] = {b0.x, b0.y, b0.z, b0.w, b1.x, b1.y, b1.z, b1.w};
  v8s uv = *(const v8s*)(uvqk + (size_t)row * U_DIM + lane * 8);
  v8s o;
#pragma unroll
  for (int j = 0; j < 8; ++j) {
    float u = bf2f((unsigned short)uv[j]);
    o[j] = (short)f2bf(u * ((v[j] - mean) * rstd * wv[j] + bv[j]));
  }
  *(v8s*)(par + (size_t)row * D_HID + lane * 8) = o;
}

// ---------------------------------------------------------------------------
// Transpose fp32 (R x C) -> bf16 (C x R).  32x32 LDS tiles.
// ---------------------------------------------------------------------------
__global__ __launch_bounds__(256) void transpose_w_kernel(
    const float* __restrict__ in, unsigned short* __restrict__ out, int R, int C)
{
  __shared__ float tile[32][33];
  int c0 = blockIdx.x * 32, r0 = blockIdx.y * 32;
  int tr = threadIdx.x >> 3;
  int tc = (threadIdx.x & 7) * 4;
  float4 vv = *(const float4*)(in + (size_t)(r0 + tr) * C + c0 + tc);
  tile[tr][tc + 0] = vv.x; tile[tr][tc + 1] = vv.y;
  tile[tr][tc + 2] = vv.z; tile[tr][tc + 3] = vv.w;
  __syncthreads();
  v4us o;
#pragma unroll
  for (int j = 0; j < 4; ++j) o[j] = f2bf(tile[tc + j][tr]);
  *(v4us*)(out + (size_t)(c0 + tr) * R + r0 + tc) = o;
}

// ---------------------------------------------------------------------------
// bf16 GEMM, 128x128 tile, BK=32, 4 waves (2x2 of 64x64), 16x16x32 MFMA.
// EPI 0: out_bf16 = silu(acc + bias[n])   (q columns additionally * ALPHA)
// EPI 1: out_f32 = acc + resid[m][n].
// ---------------------------------------------------------------------------
template <int EPI>
__global__ __launch_bounds__(256) void gemm_kernel(
    const unsigned short* __restrict__ A, const unsigned short* __restrict__ Bt,
    int K, int N,
    const float* __restrict__ bias, const float* __restrict__ resid,
    unsigned short* __restrict__ outb, float* __restrict__ outf)
{
  __shared__ unsigned short Al[128 * 40];
  __shared__ unsigned short Bl[128 * 40];
  int m0 = blockIdx.x * 128, n0 = blockIdx.y * 128;
  int tid = threadIdx.x, lane = tid & 63, wid = tid >> 6;
  int wr = wid >> 1, wc = wid & 1;
  int lr = lane & 15, lg = lane >> 4;

  v4f acc[4][4];
#pragma unroll
  for (int i = 0; i < 4; ++i)
#pragma unroll
    for (int j = 0; j < 4; ++j) acc[i][j] = (v4f){0.f, 0.f, 0.f, 0.f};

  int srow = tid >> 1;
  int sc   = (tid & 1) * 16;
  const unsigned short* ga = A  + (size_t)(m0 + srow) * K + sc;
  const unsigned short* gb = Bt + (size_t)(n0 + srow) * K + sc;

  for (int k0 = 0; k0 < K; k0 += 32) {
    v8s a0 = *(const v8s*)(ga + k0);
    v8s a1 = *(const v8s*)(ga + k0 + 8);
    v8s b0 = *(const v8s*)(gb + k0);
    v8s b1 = *(const v8s*)(gb + k0 + 8);
    *(v8s*)&Al[srow * 40 + sc]     = a0;
    *(v8s*)&Al[srow * 40 + sc + 8] = a1;
    *(v8s*)&Bl[srow * 40 + sc]     = b0;
    *(v8s*)&Bl[srow * 40 + sc + 8] = b1;
    __syncthreads();
    v8s af[4], bf[4];
#pragma unroll
    for (int mt = 0; mt < 4; ++mt) af[mt] = *(const v8s*)&Al[(wr * 64 + mt * 16 + lr) * 40 + lg * 8];
#pragma unroll
    for (int nt = 0; nt < 4; ++nt) bf[nt] = *(const v8s*)&Bl[(wc * 64 + nt * 16 + lr) * 40 + lg * 8];
#pragma unroll
    for (int mt = 0; mt < 4; ++mt)
#pragma unroll
      for (int nt = 0; nt < 4; ++nt)
        acc[mt][nt] = __builtin_amdgcn_mfma_f32_16x16x32_bf16(af[mt], bf[nt], acc[mt][nt], 0, 0, 0);
    __syncthreads();
  }

#pragma unroll
  for (int nt = 0; nt < 4; ++nt) {
    int col = n0 + wc * 64 + nt * 16 + lr;
    float bi = 0.f;
    if constexpr (EPI == 0) bi = bias[col];
#pragma unroll
    for (int mt = 0; mt < 4; ++mt) {
      int row0 = m0 + wr * 64 + mt * 16 + lg * 4;
#pragma unroll
      for (int r = 0; r < 4; ++r) {
        float xv = acc[mt][nt][r];
        if constexpr (EPI == 0) {
          float rv = siluf(xv + bi);
          if ((unsigned)(col - 2 * D_HID) < (unsigned)D_HID) rv *= ALPHA_;  // q cols
          outb[(size_t)(row0 + r) * N + col] = f2bf(rv);
        } else {
          outf[(size_t)(row0 + r) * N + col] = xv + resid[(size_t)(row0 + r) * N + col];
        }
      }
    }
  }
}

// ---------------------------------------------------------------------------
// HSTU attention, 4-way t-split.  grid = (q 4)<<7 | (b 32)<<2 | (n 4) = 512
// blocks of 512 threads (8 waves).  At ~124 VGPR the HW fits 4 waves/SIMD ->
// 2 blocks/CU resident (grid 512 / 256 CU = 2).  Each block: all 256 q rows
// of one (b,n) over 9 kv tiles of 64 (t in [q*576, q*576+576)); writes one of
// four partial-sum buffers (silu attention has no normalization).
//   Staging: thread (m = tid&15, strow = tid>>4) loads two ADJACENT t rows
//   (2*strow, 2*strow+1) x 8 d; K stored row-major via cvt_pk b128 writes;
//   V stored [d][t] with t-pair u32 writes (one cvt_pk each), XOR key
//   8*(m&7) on the t index keeping write and b128 read ~2-way free.
//   QK^T swapped (mfma(K,Q) -> S^T): P written as packed cvt_pk u32 pairs.
// ---------------------------------------------------------------------------
__global__ __launch_bounds__(512) void attn_kernel(
    const float* __restrict__ histK, const float* __restrict__ histV,
    const unsigned short* __restrict__ uvqk, float* __restrict__ attn_out)
{
  __shared__ __align__(16) unsigned short Kl[64 * 136];     // [t][d], pad 8
  __shared__ __align__(16) unsigned short Vt[128 * 72];     // [d][t^key], pad 8
  __shared__ __align__(16) unsigned short Pl[8 * 32 * 72];  // per-wave [s][t]

  int bid = blockIdx.x;
  int q   = bid >> 7;
  int b   = (bid >> 2) & 31;
  int n   = bid & 3;
  int tbase0 = q * 576;

  int tid = threadIdx.x, lane = tid & 63, w = tid >> 6;
  int lr = lane & 15, lg = lane >> 4;

  // Q fragments: qf[sb][c], rows s = w*32 + sb*16 + lr
  v8s qf[2][4];
#pragma unroll
  for (int sb = 0; sb < 2; ++sb) {
    const unsigned short* qp = uvqk + (size_t)(b * SEQ + w * 32 + sb * 16 + lr) * U_DIM
                               + 2 * D_HID + n * DHEAD + lg * 8;
#pragma unroll
    for (int c = 0; c < 4; ++c) qf[sb][c] = *(const v8s*)(qp + c * 32);
  }

  v4f oacc[2][8];
#pragma unroll
  for (int sb = 0; sb < 2; ++sb)
#pragma unroll
    for (int dt = 0; dt < 8; ++dt) oacc[sb][dt] = (v4f){0.f, 0.f, 0.f, 0.f};

  int m     = tid & 15;
  int std0  = m * 8;            // staging d offset (8 contiguous)
  int strow = tid >> 4;         // staging t-pair index (0..31)
  int vkey  = 8 * (m & 7);      // Vt t-index XOR key (shorts)

  const float* kbase = histK + (((size_t)b * HIST) * NHEAD + n) * DHEAD + std0;
  const float* vbase = histV + (((size_t)b * HIST) * NHEAD + n) * DHEAD + std0;

  // staging registers (next tile in flight)
  float4 hx[2][4];              // hist: [p][k0,k1,v0,v1]
  v8s    nx[2][2];              // new-kv: [p][k,v]
  int isnew_r = 0;

  auto stage_load = [&](int kt) {
    int tb = tbase0 + kt * 64;
    if (tb < HIST) {
      isnew_r = 0;
#pragma unroll
      for (int p = 0; p < 2; ++p) {
        size_t tg = (size_t)(tb + 2 * strow + p) * (NHEAD * DHEAD);
        hx[p][0] = *(const float4*)(kbase + tg);
        hx[p][1] = *(const float4*)(kbase + tg + 4);
        hx[p][2] = *(const float4*)(vbase + tg);
        hx[p][3] = *(const float4*)(vbase + tg + 4);
      }
    } else {
      isnew_r = 1;
#pragma unroll
      for (int p = 0; p < 2; ++p) {
        int srw = b * SEQ + (tb - HIST) + 2 * strow + p;
        nx[p][0] = *(const v8s*)(uvqk + (size_t)srw * U_DIM + 3 * D_HID + n * DHEAD + std0);
        nx[p][1] = *(const v8s*)(uvqk + (size_t)srw * U_DIM + 1 * D_HID + n * DHEAD + std0);
      }
    }
  };

  auto stage_store = [&]() {
    int t0 = 2 * strow;
    if (!isnew_r) {
#pragma unroll
      for (int p = 0; p < 2; ++p) {
        v4u kp;
        kp[0] = cvtpk(hx[p][0].x, hx[p][0].y);
        kp[1] = cvtpk(hx[p][0].z, hx[p][0].w);
        kp[2] = cvtpk(hx[p][1].x, hx[p][1].y);
        kp[3] = cvtpk(hx[p][1].z, hx[p][1].w);
        *(v4u*)&Kl[(t0 + p) * 136 + std0] = kp;
      }
      float v0[8] = {hx[0][2].x, hx[0][2].y, hx[0][2].z, hx[0][2].w,
                     hx[0][3].x, hx[0][3].y, hx[0][3].z, hx[0][3].w};
      float v1[8] = {hx[1][2].x, hx[1][2].y, hx[1][2].z, hx[1][2].w,
                     hx[1][3].x, hx[1][3].y, hx[1][3].z, hx[1][3].w};
#pragma unroll
      for (int j = 0; j < 8; ++j) {
        int d = std0 + j;
        *(unsigned int*)&Vt[d * 72 + (t0 ^ vkey)] = cvtpk(v0[j], v1[j]);
      }
    } else {
#pragma unroll
      for (int p = 0; p < 2; ++p) *(v8s*)&Kl[(t0 + p) * 136 + std0] = nx[p][0];
#pragma unroll
      for (int j = 0; j < 8; ++j) {
        int d = std0 + j;
        unsigned int pk = (unsigned int)(unsigned short)nx[0][1][j]
                        | ((unsigned int)(unsigned short)nx[1][1][j] << 16);
        *(unsigned int*)&Vt[d * 72 + (t0 ^ vkey)] = pk;
      }
    }
  };

  stage_load(0);
  stage_store();
  __syncthreads();

  unsigned short* Plw = &Pl[w * 32 * 72];

  for (int kt = 0; kt < 9; ++kt) {
    if (kt + 1 < 9) stage_load(kt + 1);    // issue next-tile loads

    int tb = tbase0 + kt * 64;
    bool masked = (tb >= HIST);            // tile entirely in new-token range

    // ---- QK^T swapped: D[t][s] = K . Q^T (alpha pre-folded into q) ----
#pragma unroll
    for (int tt = 0; tt < 4; ++tt) {
      v8s kf[4];
#pragma unroll
      for (int c = 0; c < 4; ++c)
        kf[c] = *(const v8s*)&Kl[(tt * 16 + lr) * 136 + c * 32 + lg * 8];
#pragma unroll
      for (int sb = 0; sb < 2; ++sb) {
        v4f sa = (v4f){0.f, 0.f, 0.f, 0.f};
#pragma unroll
        for (int c = 0; c < 4; ++c)
          sa = __builtin_amdgcn_mfma_f32_16x16x32_bf16(kf[c], qf[sb][c], sa, 0, 0, 0);
        int s  = w * 32 + sb * 16 + lr;     // query index within SEQ
        int t0 = tb + tt * 16 + lg * 4;     // global kv position of r=0
#pragma unroll
        for (int rp = 0; rp < 2; ++rp) {
          float p0 = siluf(sa[rp * 2]);
          float p1 = siluf(sa[rp * 2 + 1]);
          if (masked) {
            if (t0 + rp * 2     - HIST > s) p0 = 0.f;   // causal: t <= H + s
            if (t0 + rp * 2 + 1 - HIST > s) p1 = 0.f;
          }
          *(unsigned int*)&Plw[(sb * 16 + lr) * 72 + tt * 16 + lg * 4 + rp * 2] =
              cvtpk(p0, p1);
        }
      }
    }

    // ---- PV: oacc += P . V  (Pl per-wave: no barrier needed between) ----
#pragma unroll
    for (int c = 0; c < 2; ++c) {
      v8s pa[2];
#pragma unroll
      for (int sb = 0; sb < 2; ++sb)
        pa[sb] = *(const v8s*)&Plw[(sb * 16 + lr) * 72 + c * 32 + lg * 8];
#pragma unroll
      for (int dt = 0; dt < 8; ++dt) {
        int d = dt * 16 + lr;
        int rkey = 8 * ((2 * dt + (lr >> 3)) & 7);     // = 8*((d>>3)&7)
        v8s vf = *(const v8s*)&Vt[d * 72 + ((c * 32 + lg * 8) ^ rkey)];
#pragma unroll
        for (int sb = 0; sb < 2; ++sb)
          oacc[sb][dt] = __builtin_amdgcn_mfma_f32_16x16x32_bf16(pa[sb], vf, oacc[sb][dt], 0, 0, 0);
      }
    }
    __syncthreads();                        // all waves done with Kl/Vt
    if (kt + 1 < 9) {
      stage_store();                        // cvt + LDS write of next tile
      __syncthreads();
    }
  }

  // ---- epilogue: write fp32 partial rows for this t-quarter ----
#pragma unroll
  for (int sb = 0; sb < 2; ++sb) {
    int srow = b * SEQ + w * 32 + sb * 16 + lg * 4;
    float* op = attn_out + (size_t)q * ((size_t)NTOK * D_HID)
              + (size_t)srow * D_HID + n * DHEAD + lr;
#pragma unroll
    for (int dt = 0; dt < 8; ++dt)
#pragma unroll
      for (int r = 0; r < 4; ++r)
        op[(size_t)r * D_HID + dt * 16] = oacc[sb][dt][r];
  }
}

// ---------------------------------------------------------------------------
extern "C" void kernel_launch(void* const* d_in, const int* in_sizes, int n_in,
                              void* d_out, int out_size, void* d_ws, size_t ws_size,
                              hipStream_t stream)
{
  (void)in_sizes; (void)n_in; (void)out_size; (void)ws_size;

  const float* layer_input = (const float*)d_in[0];
  const float* hist_k   = (const float*)d_in[1];
  const float* hist_v   = (const float*)d_in[2];
  const float* ln_in_w  = (const float*)d_in[3];
  const float* ln_in_b  = (const float*)d_in[4];
  const float* W_uvqk   = (const float*)d_in[5];
  const float* b_uvqk   = (const float*)d_in[6];
  const float* ln_out_w = (const float*)d_in[7];
  const float* ln_out_b = (const float*)d_in[8];
  const float* W_proj   = (const float*)d_in[9];
  float* out = (float*)d_out;

  // workspace layout (x_bf dead before par is written -> share [96,104)):
  char* ws = (char*)d_ws;
  unsigned short* uvqk    = (unsigned short*)(ws);                  // [  0, 32) MiB
  float*          attn0   = (float*)         (ws + (32u  << 20));   // [ 32, 48)
  float*          attn1   = (float*)         (ws + (48u  << 20));   // [ 48, 64)
  float*          attn2   = (float*)         (ws + (64u  << 20));   // [ 64, 80)
  float*          attn3   = (float*)         (ws + (80u  << 20));   // [ 80, 96)
  unsigned short* x_bf    = (unsigned short*)(ws + (96u  << 20));   // [ 96,104)
  unsigned short* par     = (unsigned short*)(ws + (96u  << 20));   // [ 96,104)
  unsigned short* wt_uvqk = (unsigned short*)(ws + (104u << 20));   // [104,106)
  unsigned short* wt_proj = (unsigned short*)(ws + (106u << 20));   // [106,106.5)

  ln_in_kernel<<<dim3(2048), dim3(256), 0, stream>>>(layer_input, ln_in_w, ln_in_b, x_bf);
  transpose_w_kernel<<<dim3(64, 16), dim3(256), 0, stream>>>(W_uvqk, wt_uvqk, 512, 2048);
  transpose_w_kernel<<<dim3(16, 16), dim3(256), 0, stream>>>(W_proj, wt_proj, 512, 512);
  gemm_kernel<0><<<dim3(64, 16), dim3(256), 0, stream>>>(x_bf, wt_uvqk, 512, 2048,
                                                         b_uvqk, nullptr, uvqk, nullptr);
  attn_kernel<<<dim3(512), dim3(512), 0, stream>>>(hist_k, hist_v, uvqk, attn0);
  gated_ln_kernel<<<dim3(2048), dim3(256), 0, stream>>>(attn0, attn1, attn2, attn3,
                                                        uvqk, ln_out_w, ln_out_b, par);
  gemm_kernel<1><<<dim3(64, 4), dim3(256), 0, stream>>>(par, wt_proj, 512, 512,
                                                        nullptr, layer_input, nullptr, out);
}

// Round 4
// 189.164 us; speedup vs baseline: 3.1605x; 1.0606x over previous
//
#include <hip/hip_runtime.h>
#include <hip/hip_bf16.h>

// ---------------------------------------------------------------------------
// PagedHSTUInferLayer on MI355X (gfx950)
// LN -> GEMM1(bf16 MFMA, silu+bias, alpha folded into q cols) ->
// HSTU attention (2-way t-split, double-buffered K/V LDS, ONE barrier/tile) ->
// gated LN (sums two t-partials) -> GEMM2(+residual, fp32 out)
//
// NOTE (R2 lesson): attn_kernel must NOT carry a min-waves launch_bounds
// hint: forcing 4 waves/EU made the compiler allocate 64 VGPR and spill
// accumulators to scratch (WRITE_SIZE 33 MB -> 1.23 GB, 136 -> 520 us).
// NOTE (R3 lesson): per-CU work is the limiter, and 2 barriers/tile with
// serial staging left ~70% dead time -> double-buffer + single barrier.
// ---------------------------------------------------------------------------

typedef __attribute__((ext_vector_type(8))) short v8s;   // 8 x bf16 (4 VGPR)
typedef __attribute__((ext_vector_type(4))) float v4f;   // MFMA accumulator
typedef __attribute__((ext_vector_type(4))) unsigned short v4us;
typedef __attribute__((ext_vector_type(4))) unsigned int v4u;

#define D_HID 512
#define U_DIM 2048
#define NHEAD 4
#define DHEAD 128
#define BATCH 32
#define SEQ   256
#define HIST  2048
#define NTOK  8192
#define ALPHA_ 0.08838834764831845f   // 1/sqrt(128)
#define EPS_   1e-5f

__device__ __forceinline__ unsigned short f2bf(float f) {
  unsigned int u = __float_as_uint(f);
  u += 0x7FFFu + ((u >> 16) & 1u);            // round-to-nearest-even
  return (unsigned short)(u >> 16);
}
__device__ __forceinline__ float bf2f(unsigned short s) {
  return __uint_as_float(((unsigned int)s) << 16);
}
__device__ __forceinline__ float siluf(float x) {
  return x / (1.0f + __expf(-x));
}
// packed 2xf32 -> 2xbf16 (v_cvt_pk_bf16_f32), lo in bits 0-15
__device__ __forceinline__ unsigned int cvtpk(float lo, float hi) {
  __hip_bfloat162 h = __float22bfloat162_rn(make_float2(lo, hi));
  union { __hip_bfloat162 h; unsigned int u; } cv; cv.h = h;
  return cv.u;
}

// ---------------------------------------------------------------------------
// LN over D=512 per row -> bf16. 4 waves/block, one row per wave.
// ---------------------------------------------------------------------------
__global__ __launch_bounds__(256) void ln_in_kernel(
    const float* __restrict__ x, const float* __restrict__ w,
    const float* __restrict__ b, unsigned short* __restrict__ out)
{
  int wid = threadIdx.x >> 6, lane = threadIdx.x & 63;
  int row = blockIdx.x * 4 + wid;
  const float* xr = x + (size_t)row * D_HID + lane * 8;
  float4 a0 = *(const float4*)xr;
  float4 a1 = *(const float4*)(xr + 4);
  float v[8] = {a0.x, a0.y, a0.z, a0.w, a1.x, a1.y, a1.z, a1.w};
  float s = 0.f, s2 = 0.f;
#pragma unroll
  for (int j = 0; j < 8; ++j) { s += v[j]; s2 += v[j] * v[j]; }
#pragma unroll
  for (int m = 1; m < 64; m <<= 1) { s += __shfl_xor(s, m, 64); s2 += __shfl_xor(s2, m, 64); }
  float mean = s * (1.f / D_HID);
  float var  = s2 * (1.f / D_HID) - mean * mean;
  float rstd = rsqrtf(var + EPS_);
  const float* wp = w + lane * 8; const float* bp = b + lane * 8;
  float4 w0 = *(const float4*)wp, w1 = *(const float4*)(wp + 4);
  float4 b0 = *(const float4*)bp, b1 = *(const float4*)(bp + 4);
  float wv[8] = {w0.x, w0.y, w0.z, w0.w, w1.x, w1.y, w1.z, w1.w};
  float bv[8] = {b0.x, b0.y, b0.z, b0.w, b1.x, b1.y, b1.z, b1.w};
  v8s o;
#pragma unroll
  for (int j = 0; j < 8; ++j) o[j] = (short)f2bf((v[j] - mean) * rstd * wv[j] + bv[j]);
  *(v8s*)(out + (size_t)row * D_HID + lane * 8) = o;
}

// ---------------------------------------------------------------------------
// gated LN: parallel = u * LN(attn0 + attn1)
// ---------------------------------------------------------------------------
__global__ __launch_bounds__(256) void gated_ln_kernel(
    const float* __restrict__ attn0, const float* __restrict__ attn1,
    const unsigned short* __restrict__ uvqk,
    const float* __restrict__ w, const float* __restrict__ b,
    unsigned short* __restrict__ par)
{
  int wid = threadIdx.x >> 6, lane = threadIdx.x & 63;
  int row = blockIdx.x * 4 + wid;
  size_t off = (size_t)row * D_HID + lane * 8;
  float4 x0 = *(const float4*)(attn0 + off), x1 = *(const float4*)(attn0 + off + 4);
  float4 y0 = *(const float4*)(attn1 + off), y1 = *(const float4*)(attn1 + off + 4);
  float v[8] = {x0.x + y0.x, x0.y + y0.y, x0.z + y0.z, x0.w + y0.w,
                x1.x + y1.x, x1.y + y1.y, x1.z + y1.z, x1.w + y1.w};
  float s = 0.f, s2 = 0.f;
#pragma unroll
  for (int j = 0; j < 8; ++j) { s += v[j]; s2 += v[j] * v[j]; }
#pragma unroll
  for (int m = 1; m < 64; m <<= 1) { s += __shfl_xor(s, m, 64); s2 += __shfl_xor(s2, m, 64); }
  float mean = s * (1.f / D_HID);
  float var  = s2 * (1.f / D_HID) - mean * mean;
  float rstd = rsqrtf(var + EPS_);
  const float* wp = w + lane * 8; const float* bp = b + lane * 8;
  float4 w0 = *(const float4*)wp, w1 = *(const float4*)(wp + 4);
  float4 b0 = *(const float4*)bp, b1 = *(const float4*)(bp + 4);
  float wv[8] = {w0.x, w0.y, w0.z, w0.w, w1.x, w1.y, w1.z, w1.w};
  float bv[8] = {b0.x, b0.y, b0.z, b0.w, b1.x, b1.y, b1.z, b1.w};
  v8s uv = *(const v8s*)(uvqk + (size_t)row * U_DIM + lane * 8);
  v8s o;
#pragma unroll
  for (int j = 0; j < 8; ++j) {
    float u = bf2f((unsigned short)uv[j]);
    o[j] = (short)f2bf(u * ((v[j] - mean) * rstd * wv[j] + bv[j]));
  }
  *(v8s*)(par + (size_t)row * D_HID + lane * 8) = o;
}

// ---------------------------------------------------------------------------
// Transpose fp32 (R x C) -> bf16 (C x R).  32x32 LDS tiles.
// ---------------------------------------------------------------------------
__global__ __launch_bounds__(256) void transpose_w_kernel(
    const float* __restrict__ in, unsigned short* __restrict__ out, int R, int C)
{
  __shared__ float tile[32][33];
  int c0 = blockIdx.x * 32, r0 = blockIdx.y * 32;
  int tr = threadIdx.x >> 3;
  int tc = (threadIdx.x & 7) * 4;
  float4 vv = *(const float4*)(in + (size_t)(r0 + tr) * C + c0 + tc);
  tile[tr][tc + 0] = vv.x; tile[tr][tc + 1] = vv.y;
  tile[tr][tc + 2] = vv.z; tile[tr][tc + 3] = vv.w;
  __syncthreads();
  v4us o;
#pragma unroll
  for (int j = 0; j < 4; ++j) o[j] = f2bf(tile[tc + j][tr]);
  *(v4us*)(out + (size_t)(c0 + tr) * R + r0 + tc) = o;
}

// ---------------------------------------------------------------------------
// bf16 GEMM, 128x128 tile, BK=32, 4 waves (2x2 of 64x64), 16x16x32 MFMA.
// EPI 0: out_bf16 = silu(acc + bias[n])   (q columns additionally * ALPHA)
// EPI 1: out_f32 = acc + resid[m][n].
// ---------------------------------------------------------------------------
template <int EPI>
__global__ __launch_bounds__(256) void gemm_kernel(
    const unsigned short* __restrict__ A, const unsigned short* __restrict__ Bt,
    int K, int N,
    const float* __restrict__ bias, const float* __restrict__ resid,
    unsigned short* __restrict__ outb, float* __restrict__ outf)
{
  __shared__ unsigned short Al[128 * 40];
  __shared__ unsigned short Bl[128 * 40];
  int m0 = blockIdx.x * 128, n0 = blockIdx.y * 128;
  int tid = threadIdx.x, lane = tid & 63, wid = tid >> 6;
  int wr = wid >> 1, wc = wid & 1;
  int lr = lane & 15, lg = lane >> 4;

  v4f acc[4][4];
#pragma unroll
  for (int i = 0; i < 4; ++i)
#pragma unroll
    for (int j = 0; j < 4; ++j) acc[i][j] = (v4f){0.f, 0.f, 0.f, 0.f};

  int srow = tid >> 1;
  int sc   = (tid & 1) * 16;
  const unsigned short* ga = A  + (size_t)(m0 + srow) * K + sc;
  const unsigned short* gb = Bt + (size_t)(n0 + srow) * K + sc;

  for (int k0 = 0; k0 < K; k0 += 32) {
    v8s a0 = *(const v8s*)(ga + k0);
    v8s a1 = *(const v8s*)(ga + k0 + 8);
    v8s b0 = *(const v8s*)(gb + k0);
    v8s b1 = *(const v8s*)(gb + k0 + 8);
    *(v8s*)&Al[srow * 40 + sc]     = a0;
    *(v8s*)&Al[srow * 40 + sc + 8] = a1;
    *(v8s*)&Bl[srow * 40 + sc]     = b0;
    *(v8s*)&Bl[srow * 40 + sc + 8] = b1;
    __syncthreads();
    v8s af[4], bf[4];
#pragma unroll
    for (int mt = 0; mt < 4; ++mt) af[mt] = *(const v8s*)&Al[(wr * 64 + mt * 16 + lr) * 40 + lg * 8];
#pragma unroll
    for (int nt = 0; nt < 4; ++nt) bf[nt] = *(const v8s*)&Bl[(wc * 64 + nt * 16 + lr) * 40 + lg * 8];
#pragma unroll
    for (int mt = 0; mt < 4; ++mt)
#pragma unroll
      for (int nt = 0; nt < 4; ++nt)
        acc[mt][nt] = __builtin_amdgcn_mfma_f32_16x16x32_bf16(af[mt], bf[nt], acc[mt][nt], 0, 0, 0);
    __syncthreads();
  }

#pragma unroll
  for (int nt = 0; nt < 4; ++nt) {
    int col = n0 + wc * 64 + nt * 16 + lr;
    float bi = 0.f;
    if constexpr (EPI == 0) bi = bias[col];
#pragma unroll
    for (int mt = 0; mt < 4; ++mt) {
      int row0 = m0 + wr * 64 + mt * 16 + lg * 4;
#pragma unroll
      for (int r = 0; r < 4; ++r) {
        float xv = acc[mt][nt][r];
        if constexpr (EPI == 0) {
          float rv = siluf(xv + bi);
          if ((unsigned)(col - 2 * D_HID) < (unsigned)D_HID) rv *= ALPHA_;  // q cols
          outb[(size_t)(row0 + r) * N + col] = f2bf(rv);
        } else {
          outf[(size_t)(row0 + r) * N + col] = xv + resid[(size_t)(row0 + r) * N + col];
        }
      }
    }
  }
}

// ---------------------------------------------------------------------------
// HSTU attention, 2-way t-split, double-buffered K/V, single barrier/tile.
// grid = (q 2)<<7 | (b 32)<<2 | (n 4) = 256 blocks of 512 threads (8 waves)
// = exactly 1 block/CU.  Each block: all 256 q rows of one (b,n) over 18 kv
// tiles of 64 (t in [q*1152, q*1152+1152)); writes one of two partial-sum
// buffers (silu attention has no normalization -> partials additive).
//
// Per-tile schedule (2-phase template):
//   stage_store(kt+1 -> buf^1)   // cvt + LDS writes, overlaps other waves'
//   stage_load(kt+2 -> regs)     //   compute; loads 1 tile deep in flight
//   compute(kt from buf)         // QKT -> silu/mask -> P(LDS, per-wave) -> PV
//   __syncthreads()              // ONE barrier per tile
//
//   K stored row-major via cvt_pk b128 writes; V stored [d][t] with t-pair
//   u32 writes, XOR key 8*(m&7) keeping writes and b128 reads ~2-way free.
//   QK^T swapped (mfma(K,Q) -> S^T); alpha pre-folded into q by GEMM1.
// ---------------------------------------------------------------------------
__global__ __launch_bounds__(512) void attn_kernel(
    const float* __restrict__ histK, const float* __restrict__ histV,
    const unsigned short* __restrict__ uvqk, float* __restrict__ attn_out)
{
  __shared__ __align__(16) unsigned short Kl[2 * 64 * 136];   // [buf][t][d], pad 8
  __shared__ __align__(16) unsigned short Vt[2 * 128 * 72];   // [buf][d][t^key]
  __shared__ __align__(16) unsigned short Pl[8 * 32 * 72];    // per-wave [s][t]

  int bid = blockIdx.x;
  int q   = bid >> 7;
  int b   = (bid >> 2) & 31;
  int n   = bid & 3;
  int tbase0 = q * 1152;
  const int NT = 18;

  int tid = threadIdx.x, lane = tid & 63, w = tid >> 6;
  int lr = lane & 15, lg = lane >> 4;

  // Q fragments: qf[sb][c], rows s = w*32 + sb*16 + lr
  v8s qf[2][4];
#pragma unroll
  for (int sb = 0; sb < 2; ++sb) {
    const unsigned short* qp = uvqk + (size_t)(b * SEQ + w * 32 + sb * 16 + lr) * U_DIM
                               + 2 * D_HID + n * DHEAD + lg * 8;
#pragma unroll
    for (int c = 0; c < 4; ++c) qf[sb][c] = *(const v8s*)(qp + c * 32);
  }

  v4f oacc[2][8];
#pragma unroll
  for (int sb = 0; sb < 2; ++sb)
#pragma unroll
    for (int dt = 0; dt < 8; ++dt) oacc[sb][dt] = (v4f){0.f, 0.f, 0.f, 0.f};

  int m     = tid & 15;
  int std0  = m * 8;            // staging d offset (8 contiguous)
  int strow = tid >> 4;         // staging t-pair index (0..31)
  int vkey  = 8 * (m & 7);      // Vt t-index XOR key (shorts)

  const float* kbase = histK + (((size_t)b * HIST) * NHEAD + n) * DHEAD + std0;
  const float* vbase = histV + (((size_t)b * HIST) * NHEAD + n) * DHEAD + std0;

  // staging registers (next tile in flight)
  float4 hx[2][4];              // hist: [p][k0,k1,v0,v1]
  v8s    nx[2][2];              // new-kv: [p][k,v]
  int isnew_r = 0;

  auto stage_load = [&](int kt) {
    int tb = tbase0 + kt * 64;
    if (tb < HIST) {
      isnew_r = 0;
#pragma unroll
      for (int p = 0; p < 2; ++p) {
        size_t tg = (size_t)(tb + 2 * strow + p) * (NHEAD * DHEAD);
        hx[p][0] = *(const float4*)(kbase + tg);
        hx[p][1] = *(const float4*)(kbase + tg + 4);
        hx[p][2] = *(const float4*)(vbase + tg);
        hx[p][3] = *(const float4*)(vbase + tg + 4);
      }
    } else {
      isnew_r = 1;
#pragma unroll
      for (int p = 0; p < 2; ++p) {
        int srw = b * SEQ + (tb - HIST) + 2 * strow + p;
        nx[p][0] = *(const v8s*)(uvqk + (size_t)srw * U_DIM + 3 * D_HID + n * DHEAD + std0);
        nx[p][1] = *(const v8s*)(uvqk + (size_t)srw * U_DIM + 1 * D_HID + n * DHEAD + std0);
      }
    }
  };

  auto stage_store = [&](int buf) {
    unsigned short* Kb = &Kl[buf * (64 * 136)];
    unsigned short* Vb = &Vt[buf * (128 * 72)];
    int t0 = 2 * strow;
    if (!isnew_r) {
#pragma unroll
      for (int p = 0; p < 2; ++p) {
        v4u kp;
        kp[0] = cvtpk(hx[p][0].x, hx[p][0].y);
        kp[1] = cvtpk(hx[p][0].z, hx[p][0].w);
        kp[2] = cvtpk(hx[p][1].x, hx[p][1].y);
        kp[3] = cvtpk(hx[p][1].z, hx[p][1].w);
        *(v4u*)&Kb[(t0 + p) * 136 + std0] = kp;
      }
      float v0[8] = {hx[0][2].x, hx[0][2].y, hx[0][2].z, hx[0][2].w,
                     hx[0][3].x, hx[0][3].y, hx[0][3].z, hx[0][3].w};
      float v1[8] = {hx[1][2].x, hx[1][2].y, hx[1][2].z, hx[1][2].w,
                     hx[1][3].x, hx[1][3].y, hx[1][3].z, hx[1][3].w};
#pragma unroll
      for (int j = 0; j < 8; ++j) {
        int d = std0 + j;
        *(unsigned int*)&Vb[d * 72 + (t0 ^ vkey)] = cvtpk(v0[j], v1[j]);
      }
    } else {
#pragma unroll
      for (int p = 0; p < 2; ++p) *(v8s*)&Kb[(t0 + p) * 136 + std0] = nx[p][0];
#pragma unroll
      for (int j = 0; j < 8; ++j) {
        int d = std0 + j;
        unsigned int pk = (unsigned int)(unsigned short)nx[0][1][j]
                        | ((unsigned int)(unsigned short)nx[1][1][j] << 16);
        *(unsigned int*)&Vb[d * 72 + (t0 ^ vkey)] = pk;
      }
    }
  };

  // prologue: tile 0 into buf0; tile 1 loaded to regs
  stage_load(0);
  stage_store(0);
  stage_load(1);
  __syncthreads();

  unsigned short* Plw = &Pl[w * 32 * 72];

  for (int kt = 0; kt < NT; ++kt) {
    int cur = kt & 1;
    if (kt + 1 < NT) stage_store(cur ^ 1);   // tile kt+1 -> other buffer
    if (kt + 2 < NT) stage_load(kt + 2);     // issue tile kt+2 global loads

    int tb = tbase0 + kt * 64;
    bool masked = (tb >= HIST);              // tile in new-token range
    const unsigned short* Kb = &Kl[cur * (64 * 136)];
    const unsigned short* Vb = &Vt[cur * (128 * 72)];

    __builtin_amdgcn_s_setprio(1);
    // ---- QK^T swapped: D[t][s] = K . Q^T (alpha pre-folded into q) ----
#pragma unroll
    for (int tt = 0; tt < 4; ++tt) {
      v8s kf[4];
#pragma unroll
      for (int c = 0; c < 4; ++c)
        kf[c] = *(const v8s*)&Kb[(tt * 16 + lr) * 136 + c * 32 + lg * 8];
#pragma unroll
      for (int sb = 0; sb < 2; ++sb) {
        v4f sa = (v4f){0.f, 0.f, 0.f, 0.f};
#pragma unroll
        for (int c = 0; c < 4; ++c)
          sa = __builtin_amdgcn_mfma_f32_16x16x32_bf16(kf[c], qf[sb][c], sa, 0, 0, 0);
        int s  = w * 32 + sb * 16 + lr;     // query index within SEQ
        int t0 = tb + tt * 16 + lg * 4;     // global kv position of r=0
#pragma unroll
        for (int rp = 0; rp < 2; ++rp) {
          float p0 = siluf(sa[rp * 2]);
          float p1 = siluf(sa[rp * 2 + 1]);
          if (masked) {
            if (t0 + rp * 2     - HIST > s) p0 = 0.f;   // causal: t <= H + s
            if (t0 + rp * 2 + 1 - HIST > s) p1 = 0.f;
          }
          *(unsigned int*)&Plw[(sb * 16 + lr) * 72 + tt * 16 + lg * 4 + rp * 2] =
              cvtpk(p0, p1);
        }
      }
    }

    // ---- PV: oacc += P . V  (Pl per-wave: no barrier needed between) ----
#pragma unroll
    for (int c = 0; c < 2; ++c) {
      v8s pa[2];
#pragma unroll
      for (int sb = 0; sb < 2; ++sb)
        pa[sb] = *(const v8s*)&Plw[(sb * 16 + lr) * 72 + c * 32 + lg * 8];
#pragma unroll
      for (int dt = 0; dt < 8; ++dt) {
        int d = dt * 16 + lr;
        int rkey = 8 * ((2 * dt + (lr >> 3)) & 7);     // = 8*((d>>3)&7)
        v8s vf = *(const v8s*)&Vb[d * 72 + ((c * 32 + lg * 8) ^ rkey)];
#pragma unroll
        for (int sb = 0; sb < 2; ++sb)
          oacc[sb][dt] = __builtin_amdgcn_mfma_f32_16x16x32_bf16(pa[sb], vf, oacc[sb][dt], 0, 0, 0);
      }
    }
    __builtin_amdgcn_s_setprio(0);

    if (kt + 1 < NT) __syncthreads();       // buf^1 written by all; cur free
  }

  // ---- epilogue: write fp32 partial rows for this t-half ----
#pragma unroll
  for (int sb = 0; sb < 2; ++sb) {
    int srow = b * SEQ + w * 32 + sb * 16 + lg * 4;
    float* op = attn_out + (size_t)q * ((size_t)NTOK * D_HID)
              + (size_t)srow * D_HID + n * DHEAD + lr;
#pragma unroll
    for (int dt = 0; dt < 8; ++dt)
#pragma unroll
      for (int r = 0; r < 4; ++r)
        op[(size_t)r * D_HID + dt * 16] = oacc[sb][dt][r];
  }
}

// ---------------------------------------------------------------------------
extern "C" void kernel_launch(void* const* d_in, const int* in_sizes, int n_in,
                              void* d_out, int out_size, void* d_ws, size_t ws_size,
                              hipStream_t stream)
{
  (void)in_sizes; (void)n_in; (void)out_size; (void)ws_size;

  const float* layer_input = (const float*)d_in[0];
  const float* hist_k   = (const float*)d_in[1];
  const float* hist_v   = (const float*)d_in[2];
  const float* ln_in_w  = (const float*)d_in[3];
  const float* ln_in_b  = (const float*)d_in[4];
  const float* W_uvqk   = (const float*)d_in[5];
  const float* b_uvqk   = (const float*)d_in[6];
  const float* ln_out_w = (const float*)d_in[7];
  const float* ln_out_b = (const float*)d_in[8];
  const float* W_proj   = (const float*)d_in[9];
  float* out = (float*)d_out;

  // workspace layout (x_bf dead after gemm1; attn1 written by attn -> share):
  char* ws = (char*)d_ws;
  unsigned short* uvqk    = (unsigned short*)(ws);                  // [ 0,32) MiB
  float*          attn0   = (float*)         (ws + (32u << 20));    // [32,48)
  float*          attn1   = (float*)         (ws + (48u << 20));    // [48,64)
  unsigned short* x_bf    = (unsigned short*)(ws + (48u << 20));    // [48,56) (dead before attn)
  unsigned short* par     = (unsigned short*)(ws + (64u << 20));    // [64,72)
  unsigned short* wt_uvqk = (unsigned short*)(ws + (72u << 20));    // [72,74)
  unsigned short* wt_proj = (unsigned short*)(ws + (74u << 20));    // [74,74.5)

  ln_in_kernel<<<dim3(2048), dim3(256), 0, stream>>>(layer_input, ln_in_w, ln_in_b, x_bf);
  transpose_w_kernel<<<dim3(64, 16), dim3(256), 0, stream>>>(W_uvqk, wt_uvqk, 512, 2048);
  transpose_w_kernel<<<dim3(16, 16), dim3(256), 0, stream>>>(W_proj, wt_proj, 512, 512);
  gemm_kernel<0><<<dim3(64, 16), dim3(256), 0, stream>>>(x_bf, wt_uvqk, 512, 2048,
                                                         b_uvqk, nullptr, uvqk, nullptr);
  attn_kernel<<<dim3(256), dim3(512), 0, stream>>>(hist_k, hist_v, uvqk, attn0);
  gated_ln_kernel<<<dim3(2048), dim3(256), 0, stream>>>(attn0, attn1, uvqk, ln_out_w, ln_out_b, par);
  gemm_kernel<1><<<dim3(64, 4), dim3(256), 0, stream>>>(par, wt_proj, 512, 512,
                                                        nullptr, layer_input, nullptr, out);
}

// Round 5
// 173.184 us; speedup vs baseline: 3.4522x; 1.0923x over previous
//
#include <hip/hip_runtime.h>
#include <hip/hip_bf16.h>

// ---------------------------------------------------------------------------
// PagedHSTUInferLayer on MI355X (gfx950)
// LN -> GEMM1(bf16 MFMA, silu+bias, alpha folded into q cols) ->
// HSTU attention (2-way t-split, double-buffered K/V LDS, ONE barrier/tile) ->
// gated LN (sums two t-partials) -> GEMM2(+residual, fp32 out)
//
// R2 lesson: never force high waves/EU (spilled acc -> 1.2 GB scratch).
// R3/R4 lesson: schedule changes (barriers/dbuf/blocks-per-CU) don't move the
//   needle; VALU-busy is ~52us across all variants. VGPR=108 with 96 live
//   regs of state => register-starved codegen (remat/shuffle inflation).
// R5: launch_bounds(512,2) caps VGPR at 256 (LDS already limits to 1 block/CU
//   so no occupancy loss), fast-rcp silu (no fast-math => IEEE div was ~8
//   instrs), 32-bit shift addressing, PV operand swap -> float4 epilogue.
// ---------------------------------------------------------------------------

typedef __attribute__((ext_vector_type(8))) short v8s;   // 8 x bf16 (4 VGPR)
typedef __attribute__((ext_vector_type(4))) float v4f;   // MFMA accumulator
typedef __attribute__((ext_vector_type(4))) unsigned short v4us;
typedef __attribute__((ext_vector_type(4))) unsigned int v4u;

#define D_HID 512
#define U_DIM 2048
#define NHEAD 4
#define DHEAD 128
#define BATCH 32
#define SEQ   256
#define HIST  2048
#define NTOK  8192
#define ALPHA_ 0.08838834764831845f   // 1/sqrt(128)
#define EPS_   1e-5f

__device__ __forceinline__ unsigned short f2bf(float f) {
  unsigned int u = __float_as_uint(f);
  u += 0x7FFFu + ((u >> 16) & 1u);            // round-to-nearest-even
  return (unsigned short)(u >> 16);
}
__device__ __forceinline__ float bf2f(unsigned short s) {
  return __uint_as_float(((unsigned int)s) << 16);
}
// silu via fast hw reciprocal (harness has no -ffast-math; a plain '/'
// emits the full IEEE div_scale/div_fmas/div_fixup sequence)
__device__ __forceinline__ float siluf(float x) {
  return x * __builtin_amdgcn_rcpf(1.0f + __expf(-x));
}
// packed 2xf32 -> 2xbf16 (v_cvt_pk_bf16_f32), lo in bits 0-15
__device__ __forceinline__ unsigned int cvtpk(float lo, float hi) {
  __hip_bfloat162 h = __float22bfloat162_rn(make_float2(lo, hi));
  union { __hip_bfloat162 h; unsigned int u; } cv; cv.h = h;
  return cv.u;
}

// ---------------------------------------------------------------------------
// LN over D=512 per row -> bf16. 4 waves/block, one row per wave.
// ---------------------------------------------------------------------------
__global__ __launch_bounds__(256) void ln_in_kernel(
    const float* __restrict__ x, const float* __restrict__ w,
    const float* __restrict__ b, unsigned short* __restrict__ out)
{
  int wid = threadIdx.x >> 6, lane = threadIdx.x & 63;
  int row = blockIdx.x * 4 + wid;
  const float* xr = x + (size_t)row * D_HID + lane * 8;
  float4 a0 = *(const float4*)xr;
  float4 a1 = *(const float4*)(xr + 4);
  float v[8] = {a0.x, a0.y, a0.z, a0.w, a1.x, a1.y, a1.z, a1.w};
  float s = 0.f, s2 = 0.f;
#pragma unroll
  for (int j = 0; j < 8; ++j) { s += v[j]; s2 += v[j] * v[j]; }
#pragma unroll
  for (int m = 1; m < 64; m <<= 1) { s += __shfl_xor(s, m, 64); s2 += __shfl_xor(s2, m, 64); }
  float mean = s * (1.f / D_HID);
  float var  = s2 * (1.f / D_HID) - mean * mean;
  float rstd = rsqrtf(var + EPS_);
  const float* wp = w + lane * 8; const float* bp = b + lane * 8;
  float4 w0 = *(const float4*)wp, w1 = *(const float4*)(wp + 4);
  float4 b0 = *(const float4*)bp, b1 = *(const float4*)(bp + 4);
  float wv[8] = {w0.x, w0.y, w0.z, w0.w, w1.x, w1.y, w1.z, w1.w};
  float bv[8] = {b0.x, b0.y, b0.z, b0.w, b1.x, b1.y, b1.z, b1.w};
  v8s o;
#pragma unroll
  for (int j = 0; j < 8; ++j) o[j] = (short)f2bf((v[j] - mean) * rstd * wv[j] + bv[j]);
  *(v8s*)(out + (size_t)row * D_HID + lane * 8) = o;
}

// ---------------------------------------------------------------------------
// gated LN: parallel = u * LN(attn0 + attn1)
// ---------------------------------------------------------------------------
__global__ __launch_bounds__(256) void gated_ln_kernel(
    const float* __restrict__ attn0, const float* __restrict__ attn1,
    const unsigned short* __restrict__ uvqk,
    const float* __restrict__ w, const float* __restrict__ b,
    unsigned short* __restrict__ par)
{
  int wid = threadIdx.x >> 6, lane = threadIdx.x & 63;
  int row = blockIdx.x * 4 + wid;
  size_t off = (size_t)row * D_HID + lane * 8;
  float4 x0 = *(const float4*)(attn0 + off), x1 = *(const float4*)(attn0 + off + 4);
  float4 y0 = *(const float4*)(attn1 + off), y1 = *(const float4*)(attn1 + off + 4);
  float v[8] = {x0.x + y0.x, x0.y + y0.y, x0.z + y0.z, x0.w + y0.w,
                x1.x + y1.x, x1.y + y1.y, x1.z + y1.z, x1.w + y1.w};
  float s = 0.f, s2 = 0.f;
#pragma unroll
  for (int j = 0; j < 8; ++j) { s += v[j]; s2 += v[j] * v[j]; }
#pragma unroll
  for (int m = 1; m < 64; m <<= 1) { s += __shfl_xor(s, m, 64); s2 += __shfl_xor(s2, m, 64); }
  float mean = s * (1.f / D_HID);
  float var  = s2 * (1.f / D_HID) - mean * mean;
  float rstd = rsqrtf(var + EPS_);
  const float* wp = w + lane * 8; const float* bp = b + lane * 8;
  float4 w0 = *(const float4*)wp, w1 = *(const float4*)(wp + 4);
  float4 b0 = *(const float4*)bp, b1 = *(const float4*)(bp + 4);
  float wv[8] = {w0.x, w0.y, w0.z, w0.w, w1.x, w1.y, w1.z, w1.w};
  float bv[8] = {b0.x, b0.y, b0.z, b0.w, b1.x, b1.y, b1.z, b1.w};
  v8s uv = *(const v8s*)(uvqk + (size_t)row * U_DIM + lane * 8);
  v8s o;
#pragma unroll
  for (int j = 0; j < 8; ++j) {
    float u = bf2f((unsigned short)uv[j]);
    o[j] = (short)f2bf(u * ((v[j] - mean) * rstd * wv[j] + bv[j]));
  }
  *(v8s*)(par + (size_t)row * D_HID + lane * 8) = o;
}

// ---------------------------------------------------------------------------
// Transpose fp32 (R x C) -> bf16 (C x R).  32x32 LDS tiles.
// ---------------------------------------------------------------------------
__global__ __launch_bounds__(256) void transpose_w_kernel(
    const float* __restrict__ in, unsigned short* __restrict__ out, int R, int C)
{
  __shared__ float tile[32][33];
  int c0 = blockIdx.x * 32, r0 = blockIdx.y * 32;
  int tr = threadIdx.x >> 3;
  int tc = (threadIdx.x & 7) * 4;
  float4 vv = *(const float4*)(in + (size_t)(r0 + tr) * C + c0 + tc);
  tile[tr][tc + 0] = vv.x; tile[tr][tc + 1] = vv.y;
  tile[tr][tc + 2] = vv.z; tile[tr][tc + 3] = vv.w;
  __syncthreads();
  v4us o;
#pragma unroll
  for (int j = 0; j < 4; ++j) o[j] = f2bf(tile[tc + j][tr]);
  *(v4us*)(out + (size_t)(c0 + tr) * R + r0 + tc) = o;
}

// ---------------------------------------------------------------------------
// bf16 GEMM, 128x128 tile, BK=32, 4 waves (2x2 of 64x64), 16x16x32 MFMA.
// EPI 0: out_bf16 = silu(acc + bias[n])   (q columns additionally * ALPHA)
// EPI 1: out_f32 = acc + resid[m][n].
// ---------------------------------------------------------------------------
template <int EPI>
__global__ __launch_bounds__(256) void gemm_kernel(
    const unsigned short* __restrict__ A, const unsigned short* __restrict__ Bt,
    int K, int N,
    const float* __restrict__ bias, const float* __restrict__ resid,
    unsigned short* __restrict__ outb, float* __restrict__ outf)
{
  __shared__ unsigned short Al[128 * 40];
  __shared__ unsigned short Bl[128 * 40];
  int m0 = blockIdx.x * 128, n0 = blockIdx.y * 128;
  int tid = threadIdx.x, lane = tid & 63, wid = tid >> 6;
  int wr = wid >> 1, wc = wid & 1;
  int lr = lane & 15, lg = lane >> 4;

  v4f acc[4][4];
#pragma unroll
  for (int i = 0; i < 4; ++i)
#pragma unroll
    for (int j = 0; j < 4; ++j) acc[i][j] = (v4f){0.f, 0.f, 0.f, 0.f};

  int srow = tid >> 1;
  int sc   = (tid & 1) * 16;
  const unsigned short* ga = A  + (size_t)(m0 + srow) * K + sc;
  const unsigned short* gb = Bt + (size_t)(n0 + srow) * K + sc;

  for (int k0 = 0; k0 < K; k0 += 32) {
    v8s a0 = *(const v8s*)(ga + k0);
    v8s a1 = *(const v8s*)(ga + k0 + 8);
    v8s b0 = *(const v8s*)(gb + k0);
    v8s b1 = *(const v8s*)(gb + k0 + 8);
    *(v8s*)&Al[srow * 40 + sc]     = a0;
    *(v8s*)&Al[srow * 40 + sc + 8] = a1;
    *(v8s*)&Bl[srow * 40 + sc]     = b0;
    *(v8s*)&Bl[srow * 40 + sc + 8] = b1;
    __syncthreads();
    v8s af[4], bf[4];
#pragma unroll
    for (int mt = 0; mt < 4; ++mt) af[mt] = *(const v8s*)&Al[(wr * 64 + mt * 16 + lr) * 40 + lg * 8];
#pragma unroll
    for (int nt = 0; nt < 4; ++nt) bf[nt] = *(const v8s*)&Bl[(wc * 64 + nt * 16 + lr) * 40 + lg * 8];
#pragma unroll
    for (int mt = 0; mt < 4; ++mt)
#pragma unroll
      for (int nt = 0; nt < 4; ++nt)
        acc[mt][nt] = __builtin_amdgcn_mfma_f32_16x16x32_bf16(af[mt], bf[nt], acc[mt][nt], 0, 0, 0);
    __syncthreads();
  }

#pragma unroll
  for (int nt = 0; nt < 4; ++nt) {
    int col = n0 + wc * 64 + nt * 16 + lr;
    float bi = 0.f;
    if constexpr (EPI == 0) bi = bias[col];
#pragma unroll
    for (int mt = 0; mt < 4; ++mt) {
      int row0 = m0 + wr * 64 + mt * 16 + lg * 4;
#pragma unroll
      for (int r = 0; r < 4; ++r) {
        float xv = acc[mt][nt][r];
        if constexpr (EPI == 0) {
          float rv = siluf(xv + bi);
          if ((unsigned)(col - 2 * D_HID) < (unsigned)D_HID) rv *= ALPHA_;  // q cols
          outb[(size_t)(row0 + r) * N + col] = f2bf(rv);
        } else {
          outf[(size_t)(row0 + r) * N + col] = xv + resid[(size_t)(row0 + r) * N + col];
        }
      }
    }
  }
}

// ---------------------------------------------------------------------------
// HSTU attention, 2-way t-split, double-buffered K/V, single barrier/tile.
// grid = (q 2)<<7 | (b 32)<<2 | (n 4) = 256 blocks of 512 threads (8 waves)
// = exactly 1 block/CU.  Each block: all 256 q rows of one (b,n) over 18 kv
// tiles of 64; writes one of two partial-sum buffers.
//
// launch_bounds(512,2): VGPR cap 256.  LDS (108KB) limits the CU to one
// block anyway, so extra registers cost no occupancy; they stop the
// register-starved remat churn seen at VGPR=108.
// ---------------------------------------------------------------------------
__global__ __launch_bounds__(512, 2) void attn_kernel(
    const float* __restrict__ histK, const float* __restrict__ histV,
    const unsigned short* __restrict__ uvqk, float* __restrict__ attn_out)
{
  __shared__ __align__(16) unsigned short Kl[2 * 64 * 136];   // [buf][t][d], pad 8
  __shared__ __align__(16) unsigned short Vt[2 * 128 * 72];   // [buf][d][t^key]
  __shared__ __align__(16) unsigned short Pl[8 * 32 * 72];    // per-wave [s][t]

  int bid = blockIdx.x;
  int q   = bid >> 7;
  int b   = (bid >> 2) & 31;
  int n   = bid & 3;
  int tbase0 = q * 1152;
  const int NT = 18;

  int tid = threadIdx.x, lane = tid & 63, w = tid >> 6;
  int lr = lane & 15, lg = lane >> 4;

  // Q fragments: qf[sb][c], rows s = w*32 + sb*16 + lr
  v8s qf[2][4];
#pragma unroll
  for (int sb = 0; sb < 2; ++sb) {
    const unsigned short* qp = uvqk + (size_t)(b * SEQ + w * 32 + sb * 16 + lr) * U_DIM
                               + 2 * D_HID + n * DHEAD + lg * 8;
#pragma unroll
    for (int c = 0; c < 4; ++c) qf[sb][c] = *(const v8s*)(qp + c * 32);
  }

  v4f oacc[2][8];
#pragma unroll
  for (int sb = 0; sb < 2; ++sb)
#pragma unroll
    for (int dt = 0; dt < 8; ++dt) oacc[sb][dt] = (v4f){0.f, 0.f, 0.f, 0.f};

  int m     = tid & 15;
  int std0  = m * 8;            // staging d offset (8 contiguous)
  int strow = tid >> 4;         // staging t-pair index (0..31)
  int vkey  = 8 * (m & 7);      // Vt t-index XOR key (shorts)

  // hoisted staging bases (std0 folded in); per-tile offsets are 32-bit shifts
  const float* kbase = histK + (((size_t)b * HIST) * NHEAD + n) * DHEAD + std0;
  const float* vbase = histV + (((size_t)b * HIST) * NHEAD + n) * DHEAD + std0;
  const unsigned short* nkbase = uvqk + (size_t)(b * SEQ) * U_DIM + 3 * D_HID + n * DHEAD + std0;
  const unsigned short* nvbase = uvqk + (size_t)(b * SEQ) * U_DIM + 1 * D_HID + n * DHEAD + std0;

  // staging registers (next tile in flight)
  float4 hx[2][4];              // hist: [p][k0,k1,v0,v1]
  v8s    nx[2][2];              // new-kv: [p][k,v]
  int isnew_r = 0;

  auto stage_load = [&](int kt) {
    int tb = tbase0 + kt * 64;
    if (tb < HIST) {
      isnew_r = 0;
#pragma unroll
      for (int p = 0; p < 2; ++p) {
        unsigned off = ((unsigned)(tb + 2 * strow + p)) << 9;   // *512 floats
        hx[p][0] = *(const float4*)(kbase + off);
        hx[p][1] = *(const float4*)(kbase + off + 4);
        hx[p][2] = *(const float4*)(vbase + off);
        hx[p][3] = *(const float4*)(vbase + off + 4);
      }
    } else {
      isnew_r = 1;
#pragma unroll
      for (int p = 0; p < 2; ++p) {
        unsigned off = ((unsigned)(tb - HIST + 2 * strow + p)) << 11;  // *2048 shorts
        nx[p][0] = *(const v8s*)(nkbase + off);
        nx[p][1] = *(const v8s*)(nvbase + off);
      }
    }
  };

  auto stage_store = [&](int buf) {
    unsigned short* Kb = &Kl[buf * (64 * 136)];
    unsigned short* Vb = &Vt[buf * (128 * 72)];
    int t0 = 2 * strow;
    if (!isnew_r) {
#pragma unroll
      for (int p = 0; p < 2; ++p) {
        v4u kp;
        kp[0] = cvtpk(hx[p][0].x, hx[p][0].y);
        kp[1] = cvtpk(hx[p][0].z, hx[p][0].w);
        kp[2] = cvtpk(hx[p][1].x, hx[p][1].y);
        kp[3] = cvtpk(hx[p][1].z, hx[p][1].w);
        *(v4u*)&Kb[(t0 + p) * 136 + std0] = kp;
      }
      float v0[8] = {hx[0][2].x, hx[0][2].y, hx[0][2].z, hx[0][2].w,
                     hx[0][3].x, hx[0][3].y, hx[0][3].z, hx[0][3].w};
      float v1[8] = {hx[1][2].x, hx[1][2].y, hx[1][2].z, hx[1][2].w,
                     hx[1][3].x, hx[1][3].y, hx[1][3].z, hx[1][3].w};
#pragma unroll
      for (int j = 0; j < 8; ++j) {
        int d = std0 + j;
        *(unsigned int*)&Vb[d * 72 + (t0 ^ vkey)] = cvtpk(v0[j], v1[j]);
      }
    } else {
#pragma unroll
      for (int p = 0; p < 2; ++p) *(v8s*)&Kb[(t0 + p) * 136 + std0] = nx[p][0];
#pragma unroll
      for (int j = 0; j < 8; ++j) {
        int d = std0 + j;
        unsigned int pk = (unsigned int)(unsigned short)nx[0][1][j]
                        | ((unsigned int)(unsigned short)nx[1][1][j] << 16);
        *(unsigned int*)&Vb[d * 72 + (t0 ^ vkey)] = pk;
      }
    }
  };

  // prologue: tile 0 into buf0; tile 1 loaded to regs
  stage_load(0);
  stage_store(0);
  stage_load(1);
  __syncthreads();

  unsigned short* Plw = &Pl[w * 32 * 72];

  for (int kt = 0; kt < NT; ++kt) {
    int cur = kt & 1;
    if (kt + 1 < NT) stage_store(cur ^ 1);   // tile kt+1 -> other buffer
    if (kt + 2 < NT) stage_load(kt + 2);     // issue tile kt+2 global loads

    int tb = tbase0 + kt * 64;
    bool masked = (tb >= HIST);              // tile in new-token range
    const unsigned short* Kb = &Kl[cur * (64 * 136)];
    const unsigned short* Vb = &Vt[cur * (128 * 72)];

    __builtin_amdgcn_s_setprio(1);
    // ---- QK^T swapped: D[t][s] = K . Q^T (alpha pre-folded into q) ----
#pragma unroll
    for (int tt = 0; tt < 4; ++tt) {
      v8s kf[4];
#pragma unroll
      for (int c = 0; c < 4; ++c)
        kf[c] = *(const v8s*)&Kb[(tt * 16 + lr) * 136 + c * 32 + lg * 8];
#pragma unroll
      for (int sb = 0; sb < 2; ++sb) {
        v4f sa = (v4f){0.f, 0.f, 0.f, 0.f};
#pragma unroll
        for (int c = 0; c < 4; ++c)
          sa = __builtin_amdgcn_mfma_f32_16x16x32_bf16(kf[c], qf[sb][c], sa, 0, 0, 0);
        int s  = w * 32 + sb * 16 + lr;     // query index within SEQ
        int t0 = tb + tt * 16 + lg * 4;     // global kv position of r=0
#pragma unroll
        for (int rp = 0; rp < 2; ++rp) {
          float p0 = siluf(sa[rp * 2]);
          float p1 = siluf(sa[rp * 2 + 1]);
          if (masked) {
            if (t0 + rp * 2     - HIST > s) p0 = 0.f;   // causal: t <= H + s
            if (t0 + rp * 2 + 1 - HIST > s) p1 = 0.f;
          }
          *(unsigned int*)&Plw[(sb * 16 + lr) * 72 + tt * 16 + lg * 4 + rp * 2] =
              cvtpk(p0, p1);
        }
      }
    }

    // ---- PV (operand-swapped): oacc[d][s] += V^T . P^T ----
#pragma unroll
    for (int c = 0; c < 2; ++c) {
      v8s pa[2];
#pragma unroll
      for (int sb = 0; sb < 2; ++sb)
        pa[sb] = *(const v8s*)&Plw[(sb * 16 + lr) * 72 + c * 32 + lg * 8];
#pragma unroll
      for (int dt = 0; dt < 8; ++dt) {
        int d = dt * 16 + lr;
        int rkey = 8 * ((2 * dt + (lr >> 3)) & 7);     // = 8*((d>>3)&7)
        v8s vf = *(const v8s*)&Vb[d * 72 + ((c * 32 + lg * 8) ^ rkey)];
#pragma unroll
        for (int sb = 0; sb < 2; ++sb)
          oacc[sb][dt] = __builtin_amdgcn_mfma_f32_16x16x32_bf16(vf, pa[sb], oacc[sb][dt], 0, 0, 0);
      }
    }
    __builtin_amdgcn_s_setprio(0);

    if (kt + 1 < NT) __syncthreads();       // buf^1 written by all; cur free
  }

  // ---- epilogue: D[d][s] layout -> lane lr = s, regs = 4 consecutive d ----
  // float4 store per (sb, dt): row s = w*32+sb*16+lr, cols d = dt*16+lg*4..+3
#pragma unroll
  for (int sb = 0; sb < 2; ++sb) {
    float* op = attn_out + (size_t)q * ((size_t)NTOK * D_HID)
              + (size_t)(b * SEQ + w * 32 + sb * 16 + lr) * D_HID
              + n * DHEAD + lg * 4;
#pragma unroll
    for (int dt = 0; dt < 8; ++dt) {
      float4 o4 = make_float4(oacc[sb][dt][0], oacc[sb][dt][1],
                              oacc[sb][dt][2], oacc[sb][dt][3]);
      *(float4*)(op + dt * 16) = o4;
    }
  }
}

// ---------------------------------------------------------------------------
extern "C" void kernel_launch(void* const* d_in, const int* in_sizes, int n_in,
                              void* d_out, int out_size, void* d_ws, size_t ws_size,
                              hipStream_t stream)
{
  (void)in_sizes; (void)n_in; (void)out_size; (void)ws_size;

  const float* layer_input = (const float*)d_in[0];
  const float* hist_k   = (const float*)d_in[1];
  const float* hist_v   = (const float*)d_in[2];
  const float* ln_in_w  = (const float*)d_in[3];
  const float* ln_in_b  = (const float*)d_in[4];
  const float* W_uvqk   = (const float*)d_in[5];
  const float* b_uvqk   = (const float*)d_in[6];
  const float* ln_out_w = (const float*)d_in[7];
  const float* ln_out_b = (const float*)d_in[8];
  const float* W_proj   = (const float*)d_in[9];
  float* out = (float*)d_out;

  // workspace layout (x_bf dead after gemm1; attn1 written by attn -> share):
  char* ws = (char*)d_ws;
  unsigned short* uvqk    = (unsigned short*)(ws);                  // [ 0,32) MiB
  float*          attn0   = (float*)         (ws + (32u << 20));    // [32,48)
  float*          attn1   = (float*)         (ws + (48u << 20));    // [48,64)
  unsigned short* x_bf    = (unsigned short*)(ws + (48u << 20));    // [48,56) (dead before attn)
  unsigned short* par     = (unsigned short*)(ws + (64u << 20));    // [64,72)
  unsigned short* wt_uvqk = (unsigned short*)(ws + (72u << 20));    // [72,74)
  unsigned short* wt_proj = (unsigned short*)(ws + (74u << 20));    // [74,74.5)

  ln_in_kernel<<<dim3(2048), dim3(256), 0, stream>>>(layer_input, ln_in_w, ln_in_b, x_bf);
  transpose_w_kernel<<<dim3(64, 16), dim3(256), 0, stream>>>(W_uvqk, wt_uvqk, 512, 2048);
  transpose_w_kernel<<<dim3(16, 16), dim3(256), 0, stream>>>(W_proj, wt_proj, 512, 512);
  gemm_kernel<0><<<dim3(64, 16), dim3(256), 0, stream>>>(x_bf, wt_uvqk, 512, 2048,
                                                         b_uvqk, nullptr, uvqk, nullptr);
  attn_kernel<<<dim3(256), dim3(512), 0, stream>>>(hist_k, hist_v, uvqk, attn0);
  gated_ln_kernel<<<dim3(2048), dim3(256), 0, stream>>>(attn0, attn1, uvqk, ln_out_w, ln_out_b, par);
  gemm_kernel<1><<<dim3(64, 4), dim3(256), 0, stream>>>(par, wt_proj, 512, 512,
                                                        nullptr, layer_input, nullptr, out);
}

// Round 6
// 170.307 us; speedup vs baseline: 3.5105x; 1.0169x over previous
//
#include <hip/hip_runtime.h>
#include <hip/hip_bf16.h>

// ---------------------------------------------------------------------------
// PagedHSTUInferLayer on MI355X (gfx950)
// LN -> GEMM1(bf16 MFMA, silu+bias, alpha folded into q cols) ->
// HSTU attention (2-way t-split, 32x32x16 MFMA, P in registers via
// cvt_pk + shfl_xor(32), double-buffered swizzled K/V LDS, 1 barrier/tile) ->
// gated LN (sums two t-partials) -> GEMM2(+residual, fp32 out)
//
// R2 lesson: never force high waves/EU (spilled acc -> 1.2 GB scratch).
// R3/R4 lesson: schedule-only changes don't move attn; it is issue-bound.
// R5 lesson: VALU cuts gave 130->114; remaining cost = instruction volume.
// R6: 32x32x16 MFMA halves MFMA count; swapped QK^T (D[t][s], col=s) makes
//   P's PV-fragment lane-local up to a lane<32/>=32 half-swap -> P never
//   touches LDS (the old Pl write+read+RAW-stall is gone). K/V swizzles
//   rederived for the new patterns (conflict-free b128 reads).
// ---------------------------------------------------------------------------

typedef __attribute__((ext_vector_type(8))) short v8s;    // 8 x bf16 (4 VGPR)
typedef __attribute__((ext_vector_type(4))) float v4f;    // 16x16 accumulator
typedef __attribute__((ext_vector_type(16))) float v16f;  // 32x32 accumulator
typedef __attribute__((ext_vector_type(4))) unsigned short v4us;
typedef __attribute__((ext_vector_type(4))) unsigned int v4u;

#define D_HID 512
#define U_DIM 2048
#define NHEAD 4
#define DHEAD 128
#define BATCH 32
#define SEQ   256
#define HIST  2048
#define NTOK  8192
#define ALPHA_ 0.08838834764831845f   // 1/sqrt(128)
#define EPS_   1e-5f

__device__ __forceinline__ unsigned short f2bf(float f) {
  unsigned int u = __float_as_uint(f);
  u += 0x7FFFu + ((u >> 16) & 1u);            // round-to-nearest-even
  return (unsigned short)(u >> 16);
}
__device__ __forceinline__ float bf2f(unsigned short s) {
  return __uint_as_float(((unsigned int)s) << 16);
}
// silu via fast hw reciprocal (harness has no -ffast-math)
__device__ __forceinline__ float siluf(float x) {
  return x * __builtin_amdgcn_rcpf(1.0f + __expf(-x));
}
// packed 2xf32 -> 2xbf16 (v_cvt_pk_bf16_f32), lo in bits 0-15
__device__ __forceinline__ unsigned int cvtpk(float lo, float hi) {
  __hip_bfloat162 h = __float22bfloat162_rn(make_float2(lo, hi));
  union { __hip_bfloat162 h; unsigned int u; } cv; cv.h = h;
  return cv.u;
}

// ---------------------------------------------------------------------------
// LN over D=512 per row -> bf16. 4 waves/block, one row per wave.
// ---------------------------------------------------------------------------
__global__ __launch_bounds__(256) void ln_in_kernel(
    const float* __restrict__ x, const float* __restrict__ w,
    const float* __restrict__ b, unsigned short* __restrict__ out)
{
  int wid = threadIdx.x >> 6, lane = threadIdx.x & 63;
  int row = blockIdx.x * 4 + wid;
  const float* xr = x + (size_t)row * D_HID + lane * 8;
  float4 a0 = *(const float4*)xr;
  float4 a1 = *(const float4*)(xr + 4);
  float v[8] = {a0.x, a0.y, a0.z, a0.w, a1.x, a1.y, a1.z, a1.w};
  float s = 0.f, s2 = 0.f;
#pragma unroll
  for (int j = 0; j < 8; ++j) { s += v[j]; s2 += v[j] * v[j]; }
#pragma unroll
  for (int m = 1; m < 64; m <<= 1) { s += __shfl_xor(s, m, 64); s2 += __shfl_xor(s2, m, 64); }
  float mean = s * (1.f / D_HID);
  float var  = s2 * (1.f / D_HID) - mean * mean;
  float rstd = rsqrtf(var + EPS_);
  const float* wp = w + lane * 8; const float* bp = b + lane * 8;
  float4 w0 = *(const float4*)wp, w1 = *(const float4*)(wp + 4);
  float4 b0 = *(const float4*)bp, b1 = *(const float4*)(bp + 4);
  float wv[8] = {w0.x, w0.y, w0.z, w0.w, w1.x, w1.y, w1.z, w1.w};
  float bv[8] = {b0.x, b0.y, b0.z, b0.w, b1.x, b1.y, b1.z, b1.w};
  v8s o;
#pragma unroll
  for (int j = 0; j < 8; ++j) o[j] = (short)f2bf((v[j] - mean) * rstd * wv[j] + bv[j]);
  *(v8s*)(out + (size_t)row * D_HID + lane * 8) = o;
}

// ---------------------------------------------------------------------------
// gated LN: parallel = u * LN(attn0 + attn1)
// ---------------------------------------------------------------------------
__global__ __launch_bounds__(256) void gated_ln_kernel(
    const float* __restrict__ attn0, const float* __restrict__ attn1,
    const unsigned short* __restrict__ uvqk,
    const float* __restrict__ w, const float* __restrict__ b,
    unsigned short* __restrict__ par)
{
  int wid = threadIdx.x >> 6, lane = threadIdx.x & 63;
  int row = blockIdx.x * 4 + wid;
  size_t off = (size_t)row * D_HID + lane * 8;
  float4 x0 = *(const float4*)(attn0 + off), x1 = *(const float4*)(attn0 + off + 4);
  float4 y0 = *(const float4*)(attn1 + off), y1 = *(const float4*)(attn1 + off + 4);
  float v[8] = {x0.x + y0.x, x0.y + y0.y, x0.z + y0.z, x0.w + y0.w,
                x1.x + y1.x, x1.y + y1.y, x1.z + y1.z, x1.w + y1.w};
  float s = 0.f, s2 = 0.f;
#pragma unroll
  for (int j = 0; j < 8; ++j) { s += v[j]; s2 += v[j] * v[j]; }
#pragma unroll
  for (int m = 1; m < 64; m <<= 1) { s += __shfl_xor(s, m, 64); s2 += __shfl_xor(s2, m, 64); }
  float mean = s * (1.f / D_HID);
  float var  = s2 * (1.f / D_HID) - mean * mean;
  float rstd = rsqrtf(var + EPS_);
  const float* wp = w + lane * 8; const float* bp = b + lane * 8;
  float4 w0 = *(const float4*)wp, w1 = *(const float4*)(wp + 4);
  float4 b0 = *(const float4*)bp, b1 = *(const float4*)(bp + 4);
  float wv[8] = {w0.x, w0.y, w0.z, w0.w, w1.x, w1.y, w1.z, w1.w};
  float bv[8] = {b0.x, b0.y, b0.z, b0.w, b1.x, b1.y, b1.z, b1.w};
  v8s uv = *(const v8s*)(uvqk + (size_t)row * U_DIM + lane * 8);
  v8s o;
#pragma unroll
  for (int j = 0; j < 8; ++j) {
    float u = bf2f((unsigned short)uv[j]);
    o[j] = (short)f2bf(u * ((v[j] - mean) * rstd * wv[j] + bv[j]));
  }
  *(v8s*)(par + (size_t)row * D_HID + lane * 8) = o;
}

// ---------------------------------------------------------------------------
// Transpose fp32 (R x C) -> bf16 (C x R).  32x32 LDS tiles.
// ---------------------------------------------------------------------------
__global__ __launch_bounds__(256) void transpose_w_kernel(
    const float* __restrict__ in, unsigned short* __restrict__ out, int R, int C)
{
  __shared__ float tile[32][33];
  int c0 = blockIdx.x * 32, r0 = blockIdx.y * 32;
  int tr = threadIdx.x >> 3;
  int tc = (threadIdx.x & 7) * 4;
  float4 vv = *(const float4*)(in + (size_t)(r0 + tr) * C + c0 + tc);
  tile[tr][tc + 0] = vv.x; tile[tr][tc + 1] = vv.y;
  tile[tr][tc + 2] = vv.z; tile[tr][tc + 3] = vv.w;
  __syncthreads();
  v4us o;
#pragma unroll
  for (int j = 0; j < 4; ++j) o[j] = f2bf(tile[tc + j][tr]);
  *(v4us*)(out + (size_t)(c0 + tr) * R + r0 + tc) = o;
}

// ---------------------------------------------------------------------------
// bf16 GEMM, 128x128 tile, BK=32, 4 waves (2x2 of 64x64), 16x16x32 MFMA.
// EPI 0: out_bf16 = silu(acc + bias[n])   (q columns additionally * ALPHA)
// EPI 1: out_f32 = acc + resid[m][n].
// ---------------------------------------------------------------------------
template <int EPI>
__global__ __launch_bounds__(256) void gemm_kernel(
    const unsigned short* __restrict__ A, const unsigned short* __restrict__ Bt,
    int K, int N,
    const float* __restrict__ bias, const float* __restrict__ resid,
    unsigned short* __restrict__ outb, float* __restrict__ outf)
{
  __shared__ unsigned short Al[128 * 40];
  __shared__ unsigned short Bl[128 * 40];
  int m0 = blockIdx.x * 128, n0 = blockIdx.y * 128;
  int tid = threadIdx.x, lane = tid & 63, wid = tid >> 6;
  int wr = wid >> 1, wc = wid & 1;
  int lr = lane & 15, lg = lane >> 4;

  v4f acc[4][4];
#pragma unroll
  for (int i = 0; i < 4; ++i)
#pragma unroll
    for (int j = 0; j < 4; ++j) acc[i][j] = (v4f){0.f, 0.f, 0.f, 0.f};

  int srow = tid >> 1;
  int sc   = (tid & 1) * 16;
  const unsigned short* ga = A  + (size_t)(m0 + srow) * K + sc;
  const unsigned short* gb = Bt + (size_t)(n0 + srow) * K + sc;

  for (int k0 = 0; k0 < K; k0 += 32) {
    v8s a0 = *(const v8s*)(ga + k0);
    v8s a1 = *(const v8s*)(ga + k0 + 8);
    v8s b0 = *(const v8s*)(gb + k0);
    v8s b1 = *(const v8s*)(gb + k0 + 8);
    *(v8s*)&Al[srow * 40 + sc]     = a0;
    *(v8s*)&Al[srow * 40 + sc + 8] = a1;
    *(v8s*)&Bl[srow * 40 + sc]     = b0;
    *(v8s*)&Bl[srow * 40 + sc + 8] = b1;
    __syncthreads();
    v8s af[4], bf[4];
#pragma unroll
    for (int mt = 0; mt < 4; ++mt) af[mt] = *(const v8s*)&Al[(wr * 64 + mt * 16 + lr) * 40 + lg * 8];
#pragma unroll
    for (int nt = 0; nt < 4; ++nt) bf[nt] = *(const v8s*)&Bl[(wc * 64 + nt * 16 + lr) * 40 + lg * 8];
#pragma unroll
    for (int mt = 0; mt < 4; ++mt)
#pragma unroll
      for (int nt = 0; nt < 4; ++nt)
        acc[mt][nt] = __builtin_amdgcn_mfma_f32_16x16x32_bf16(af[mt], bf[nt], acc[mt][nt], 0, 0, 0);
    __syncthreads();
  }

#pragma unroll
  for (int nt = 0; nt < 4; ++nt) {
    int col = n0 + wc * 64 + nt * 16 + lr;
    float bi = 0.f;
    if constexpr (EPI == 0) bi = bias[col];
#pragma unroll
    for (int mt = 0; mt < 4; ++mt) {
      int row0 = m0 + wr * 64 + mt * 16 + lg * 4;
#pragma unroll
      for (int r = 0; r < 4; ++r) {
        float xv = acc[mt][nt][r];
        if constexpr (EPI == 0) {
          float rv = siluf(xv + bi);
          if ((unsigned)(col - 2 * D_HID) < (unsigned)D_HID) rv *= ALPHA_;  // q cols
          outb[(size_t)(row0 + r) * N + col] = f2bf(rv);
        } else {
          outf[(size_t)(row0 + r) * N + col] = xv + resid[(size_t)(row0 + r) * N + col];
        }
      }
    }
  }
}

// ---------------------------------------------------------------------------
// HSTU attention, 2-way t-split, 32x32x16 MFMA, in-register P.
// grid = (q 2)<<7 | (b 32)<<2 | (n 4) = 256 blocks of 512 threads (8 waves).
// Wave w owns q rows w*32 + (lane&31).  18 kv tiles of 64 per block.
//
// QK^T swapped: mfma(K, Q) -> D[t][s] with col = s = lane&31 and
// row t = (r&3)+8*(r>>2)+4*(lane>>5).  PV's B-operand needs P[s=lane&31]
// [t = hi*8 + j] -> same s per lane; only the t in [4,8)/[8,12) halves live
// on the partner lane (lane^32): cvt_pk pairs + __shfl_xor(32) + select
// assemble the fragment -> P never goes through LDS.
//
// LDS: Kl[2][64][128] swizzle col^=((t&7)<<3);  Vt[2][128][64] (V^T) swizzle
// col^=(((d>>3)^d)&7)<<3 -> conflict-free ds_read_b128, ~2-way writes.
// ---------------------------------------------------------------------------
__global__ __launch_bounds__(512, 2) void attn_kernel(
    const float* __restrict__ histK, const float* __restrict__ histV,
    const unsigned short* __restrict__ uvqk, float* __restrict__ attn_out)
{
  __shared__ __align__(16) unsigned short Kl[2 * 64 * 128];   // [buf][t][d^swz]
  __shared__ __align__(16) unsigned short Vt[2 * 128 * 64];   // [buf][d][t^swz]

  int bid = blockIdx.x;
  int q   = bid >> 7;
  int b   = (bid >> 2) & 31;
  int n   = bid & 3;
  int tbase0 = q * 1152;
  const int NT = 18;

  int tid = threadIdx.x, lane = tid & 63, w = tid >> 6;
  int l5 = lane & 31;
  int hi = lane >> 5;            // 0 / 1
  int hi8 = hi * 8;
  int sq = w * 32 + l5;          // this lane's query row within SEQ

  // Q fragments (B-operand): lane holds Q[s=l5][k = ks*16 + hi*8 + j]
  v8s qf[8];
  {
    const unsigned short* qp = uvqk + (size_t)(b * SEQ + sq) * U_DIM
                               + 2 * D_HID + n * DHEAD + hi8;
#pragma unroll
    for (int ks = 0; ks < 8; ++ks) qf[ks] = *(const v8s*)(qp + ks * 16);
  }

  v16f oacc[4];
#pragma unroll
  for (int i = 0; i < 4; ++i)
#pragma unroll
    for (int r = 0; r < 16; ++r) oacc[i][r] = 0.f;

  int m     = tid & 15;
  int std0  = m * 8;            // staging d offset (8 contiguous)
  int strow = tid >> 4;         // staging t-pair index (0..31)

  const float* kbase = histK + (((size_t)b * HIST) * NHEAD + n) * DHEAD + std0;
  const float* vbase = histV + (((size_t)b * HIST) * NHEAD + n) * DHEAD + std0;
  const unsigned short* nkbase = uvqk + (size_t)(b * SEQ) * U_DIM + 3 * D_HID + n * DHEAD + std0;
  const unsigned short* nvbase = uvqk + (size_t)(b * SEQ) * U_DIM + 1 * D_HID + n * DHEAD + std0;

  // staging registers (next tile in flight)
  float4 hx[2][4];              // hist: [p][k0,k1,v0,v1]
  v8s    nx[2][2];              // new-kv: [p][k,v]
  int isnew_r = 0;

  auto stage_load = [&](int kt) {
    int tb = tbase0 + kt * 64;
    if (tb < HIST) {
      isnew_r = 0;
#pragma unroll
      for (int p = 0; p < 2; ++p) {
        unsigned off = ((unsigned)(tb + 2 * strow + p)) << 9;   // *512 floats
        hx[p][0] = *(const float4*)(kbase + off);
        hx[p][1] = *(const float4*)(kbase + off + 4);
        hx[p][2] = *(const float4*)(vbase + off);
        hx[p][3] = *(const float4*)(vbase + off + 4);
      }
    } else {
      isnew_r = 1;
#pragma unroll
      for (int p = 0; p < 2; ++p) {
        unsigned off = ((unsigned)(tb - HIST + 2 * strow + p)) << 11;  // *2048 shorts
        nx[p][0] = *(const v8s*)(nkbase + off);
        nx[p][1] = *(const v8s*)(nvbase + off);
      }
    }
  };

  auto stage_store = [&](int buf) {
    unsigned short* Kb = &Kl[buf * 8192];
    unsigned short* Vb = &Vt[buf * 8192];
    int t0 = 2 * strow;
    if (!isnew_r) {
#pragma unroll
      for (int p = 0; p < 2; ++p) {
        int t = t0 + p;
        v4u kp;
        kp[0] = cvtpk(hx[p][0].x, hx[p][0].y);
        kp[1] = cvtpk(hx[p][0].z, hx[p][0].w);
        kp[2] = cvtpk(hx[p][1].x, hx[p][1].y);
        kp[3] = cvtpk(hx[p][1].z, hx[p][1].w);
        *(v4u*)&Kb[t * 128 + (std0 ^ ((t & 7) << 3))] = kp;
      }
      float v0[8] = {hx[0][2].x, hx[0][2].y, hx[0][2].z, hx[0][2].w,
                     hx[0][3].x, hx[0][3].y, hx[0][3].z, hx[0][3].w};
      float v1[8] = {hx[1][2].x, hx[1][2].y, hx[1][2].z, hx[1][2].w,
                     hx[1][3].x, hx[1][3].y, hx[1][3].z, hx[1][3].w};
#pragma unroll
      for (int j = 0; j < 8; ++j) {
        int d = std0 + j;
        int col = t0 ^ ((((d >> 3) ^ d) & 7) << 3);
        *(unsigned int*)&Vb[d * 64 + col] = cvtpk(v0[j], v1[j]);
      }
    } else {
#pragma unroll
      for (int p = 0; p < 2; ++p) {
        int t = t0 + p;
        *(v8s*)&Kb[t * 128 + (std0 ^ ((t & 7) << 3))] = nx[p][0];
      }
#pragma unroll
      for (int j = 0; j < 8; ++j) {
        int d = std0 + j;
        int col = t0 ^ ((((d >> 3) ^ d) & 7) << 3);
        unsigned int pk = (unsigned int)(unsigned short)nx[0][1][j]
                        | ((unsigned int)(unsigned short)nx[1][1][j] << 16);
        *(unsigned int*)&Vb[d * 64 + col] = pk;
      }
    }
  };

  // prologue: tile 0 into buf0; tile 1 loaded to regs
  stage_load(0);
  stage_store(0);
  stage_load(1);
  __syncthreads();

  for (int kt = 0; kt < NT; ++kt) {
    int cur = kt & 1;
    if (kt + 1 < NT) stage_store(cur ^ 1);   // tile kt+1 -> other buffer
    if (kt + 2 < NT) stage_load(kt + 2);     // issue tile kt+2 global loads

    int tb = tbase0 + kt * 64;
    bool masked = (tb >= HIST);              // tile in new-token range
    const unsigned short* Kb = &Kl[cur * 8192];
    const unsigned short* Vb = &Vt[cur * 8192];

    __builtin_amdgcn_s_setprio(1);

    // ---- QK^T swapped (32x32x16): D[t][s], then silu/mask/pack in regs ----
    v8s pb[4];                               // PV B-fragments, ks = 0..3
#pragma unroll
    for (int tt = 0; tt < 2; ++tt) {
      v16f sa;
#pragma unroll
      for (int r = 0; r < 16; ++r) sa[r] = 0.f;
      int trow = tt * 32 + l5;
      int kx = (trow & 7) << 3;
      int krow = trow * 128;
#pragma unroll
      for (int ks = 0; ks < 8; ++ks) {
        v8s kf = *(const v8s*)&Kb[krow + ((ks * 16 + hi8) ^ kx)];
        sa = __builtin_amdgcn_mfma_f32_32x32x16_bf16(kf, qf[ks], sa, 0, 0, 0);
      }
      unsigned e[8];
      if (masked) {
        int thr = sq - (tb - HIST) - tt * 32 - 4 * hi;   // keep if tl <= thr
#pragma unroll
        for (int i = 0; i < 8; ++i) {
          int r0 = 2 * i, r1 = 2 * i + 1;
          int tl0 = (r0 & 3) + 8 * (r0 >> 2);
          int tl1 = (r1 & 3) + 8 * (r1 >> 2);
          float p0 = (tl0 <= thr) ? siluf(sa[r0]) : 0.f;
          float p1 = (tl1 <= thr) ? siluf(sa[r1]) : 0.f;
          e[i] = cvtpk(p0, p1);
        }
      } else {
#pragma unroll
        for (int i = 0; i < 8; ++i) e[i] = cvtpk(siluf(sa[2 * i]), siluf(sa[2 * i + 1]));
      }
      // assemble PV B-fragments: lane needs t = hi*8 + j per k-step of 16
#pragma unroll
      for (int h = 0; h < 2; ++h) {
        unsigned a0 = e[h * 4 + 0], a1 = e[h * 4 + 1];
        unsigned b0 = e[h * 4 + 2], b1 = e[h * 4 + 3];
        unsigned sa0 = (unsigned)__shfl_xor((int)a0, 32, 64);
        unsigned sa1 = (unsigned)__shfl_xor((int)a1, 32, 64);
        unsigned sb0 = (unsigned)__shfl_xor((int)b0, 32, 64);
        unsigned sb1 = (unsigned)__shfl_xor((int)b1, 32, 64);
        union { unsigned u[4]; v8s s; } U;
        U.u[0] = hi ? sb0 : a0;
        U.u[1] = hi ? sb1 : a1;
        U.u[2] = hi ? b0 : sa0;
        U.u[3] = hi ? b1 : sa1;
        pb[tt * 2 + h] = U.s;
      }
    }

    // ---- PV: oacc[d][s] += V^T . P^T  (A = Vt rows, B = pb, all in regs) ----
#pragma unroll
    for (int ks = 0; ks < 4; ++ks) {
#pragma unroll
      for (int dt4 = 0; dt4 < 4; ++dt4) {
        int d = dt4 * 32 + l5;
        int col = (ks * 16 + hi8) ^ ((((d >> 3) ^ d) & 7) << 3);
        v8s vf = *(const v8s*)&Vb[d * 64 + col];
        oacc[dt4] = __builtin_amdgcn_mfma_f32_32x32x16_bf16(vf, pb[ks], oacc[dt4], 0, 0, 0);
      }
    }
    __builtin_amdgcn_s_setprio(0);

    if (kt + 1 < NT) __syncthreads();       // buf^1 written by all; cur free
  }

  // ---- epilogue: D[d][s]: col = s = l5 (one q-row per lane), row = d via
  // (r&3)+8*(r>>2)+4*hi -> regs 4g..4g+3 are 4 consecutive d -> float4 ----
  {
    float* op = attn_out + (size_t)q * ((size_t)NTOK * D_HID)
              + (size_t)(b * SEQ + sq) * D_HID + n * DHEAD + 4 * hi;
#pragma unroll
    for (int dt4 = 0; dt4 < 4; ++dt4) {
#pragma unroll
      for (int g = 0; g < 4; ++g) {
        float4 o4 = make_float4(oacc[dt4][4 * g + 0], oacc[dt4][4 * g + 1],
                                oacc[dt4][4 * g + 2], oacc[dt4][4 * g + 3]);
        *(float4*)(op + dt4 * 32 + 8 * g) = o4;
      }
    }
  }
}

// ---------------------------------------------------------------------------
extern "C" void kernel_launch(void* const* d_in, const int* in_sizes, int n_in,
                              void* d_out, int out_size, void* d_ws, size_t ws_size,
                              hipStream_t stream)
{
  (void)in_sizes; (void)n_in; (void)out_size; (void)ws_size;

  const float* layer_input = (const float*)d_in[0];
  const float* hist_k   = (const float*)d_in[1];
  const float* hist_v   = (const float*)d_in[2];
  const float* ln_in_w  = (const float*)d_in[3];
  const float* ln_in_b  = (const float*)d_in[4];
  const float* W_uvqk   = (const float*)d_in[5];
  const float* b_uvqk   = (const float*)d_in[6];
  const float* ln_out_w = (const float*)d_in[7];
  const float* ln_out_b = (const float*)d_in[8];
  const float* W_proj   = (const float*)d_in[9];
  float* out = (float*)d_out;

  // workspace layout (x_bf dead after gemm1; attn1 written by attn -> share):
  char* ws = (char*)d_ws;
  unsigned short* uvqk    = (unsigned short*)(ws);                  // [ 0,32) MiB
  float*          attn0   = (float*)         (ws + (32u << 20));    // [32,48)
  float*          attn1   = (float*)         (ws + (48u << 20));    // [48,64)
  unsigned short* x_bf    = (unsigned short*)(ws + (48u << 20));    // [48,56) (dead before attn)
  unsigned short* par     = (unsigned short*)(ws + (64u << 20));    // [64,72)
  unsigned short* wt_uvqk = (unsigned short*)(ws + (72u << 20));    // [72,74)
  unsigned short* wt_proj = (unsigned short*)(ws + (74u << 20));    // [74,74.5)

  ln_in_kernel<<<dim3(2048), dim3(256), 0, stream>>>(layer_input, ln_in_w, ln_in_b, x_bf);
  transpose_w_kernel<<<dim3(64, 16), dim3(256), 0, stream>>>(W_uvqk, wt_uvqk, 512, 2048);
  transpose_w_kernel<<<dim3(16, 16), dim3(256), 0, stream>>>(W_proj, wt_proj, 512, 512);
  gemm_kernel<0><<<dim3(64, 16), dim3(256), 0, stream>>>(x_bf, wt_uvqk, 512, 2048,
                                                         b_uvqk, nullptr, uvqk, nullptr);
  attn_kernel<<<dim3(256), dim3(512), 0, stream>>>(hist_k, hist_v, uvqk, attn0);
  gated_ln_kernel<<<dim3(2048), dim3(256), 0, stream>>>(attn0, attn1, uvqk, ln_out_w, ln_out_b, par);
  gemm_kernel<1><<<dim3(64, 4), dim3(256), 0, stream>>>(par, wt_proj, 512, 512,
                                                        nullptr, layer_input, nullptr, out);
}